// Round 9
// baseline (733.237 us; speedup 1.0000x reference)
//
#include <hip/hip_runtime.h>
#include <hip/hip_bf16.h>
#include <math.h>

// ---------------------------------------------------------------------------
// EvolveGCNH + GCNConv + EdgeDecoder.
// R1: atomic scatter -> dst-CSR register gather (3574 -> 1223 us).
// R3/R4: bf16 MFMA GEMMs, bf16 operands, src-CSR grouped decode.
// R5: parallel top-k, merged CSR builds, dual GEMM (962 us).
// R7: two-phase bucket sort for both CSRs (609 us).
// R8: quad decomposition gather/decode + kernel fusion (522 us; decode at
//     3.2 TB/s vs 3.6 achievable; p2 only 98 blocks = under-occupied).
// R9: (a) 8-lane decomposition (8 edges/wave in flight, 3-step reduce);
//     (b) 391 buckets (128 nodes each) + merged p1 / merged p2 launches
//         -> sort path fully occupies the GPU;
//     (c) hist12 folded into score_cast (global atomics); 13 launches.
// ---------------------------------------------------------------------------

typedef __attribute__((ext_vector_type(8))) short bf16x8;
typedef __attribute__((ext_vector_type(8))) unsigned short u16x8;
typedef __attribute__((ext_vector_type(4))) float f32x4;

#define WSHIFT 7              // 128 nodes per bucket
#define WMASK 127
#define NBUCK 391             // ceil(50000/128)

__device__ __forceinline__ unsigned f2key(float f) {
  unsigned u = __float_as_uint(f);
  return (u & 0x80000000u) ? ~u : (u | 0x80000000u);
}

// round-to-nearest-even fp32 -> bf16 bits
__device__ __forceinline__ unsigned short f2bf(float f) {
  unsigned u = __float_as_uint(f);
  unsigned r = u + 0x7fffu + ((u >> 16) & 1u);
  return (unsigned short)(r >> 16);
}
__device__ __forceinline__ float bf2f(unsigned short h) {
  return __uint_as_float((unsigned)h << 16);
}

__global__ void zero_kernel(float4* __restrict__ p, int n4) {
  int i = blockIdx.x * blockDim.x + threadIdx.x;
  if (i < n4) p[i] = make_float4(0.f, 0.f, 0.f, 0.f);
}

// score (incl. ||p||) + bf16 cast of x + 12-bit score histogram, one pass
__global__ __launch_bounds__(256) void score_cast_kernel(const float* __restrict__ x,
                                                         const float* __restrict__ p,
                                                         float* __restrict__ score,
                                                         unsigned short* __restrict__ xh,
                                                         int* __restrict__ ghist, int N) {
  int node = blockIdx.x * 4 + (threadIdx.x >> 6);
  int lane = threadIdx.x & 63;
  if (node >= N) return;
  float4 xv = ((const float4*)(x + (size_t)node * 256))[lane];
  ushort4 hv;
  hv.x = f2bf(xv.x);
  hv.y = f2bf(xv.y);
  hv.z = f2bf(xv.z);
  hv.w = f2bf(xv.w);
  ((ushort4*)(xh + (size_t)node * 256))[lane] = hv;
  float4 pv = ((const float4*)p)[lane];
  float s = xv.x * pv.x + xv.y * pv.y + xv.z * pv.z + xv.w * pv.w;
  float sp = pv.x * pv.x + pv.y * pv.y + pv.z * pv.z + pv.w * pv.w;
#pragma unroll
  for (int off = 32; off > 0; off >>= 1) {
    s += __shfl_down(s, off, 64);
    sp += __shfl_down(sp, off, 64);
  }
  if (lane == 0) {
    float sc = s / sqrtf(sp);
    score[node] = sc;
    atomicAdd(&ghist[f2key(sc) >> 20], 1);
  }
}

// select (suffix-scan over 4096-bin histogram -> bin-floor threshold) fused
// with collect + bitonic sort (key desc, idx asc) -> perm[k], tanh(score).
__global__ __launch_bounds__(1024) void topk_kernel(const float* __restrict__ score, int n, int k,
                                                    const int* __restrict__ gh,
                                                    int* __restrict__ perm,
                                                    float* __restrict__ tts) {
  __shared__ int part[1024];
  __shared__ unsigned sT;
  int tid = threadIdx.x;
  {
    int b0 = tid * 4;
    int s0 = gh[b0], s1 = gh[b0 + 1], s2 = gh[b0 + 2], s3 = gh[b0 + 3];
    part[tid] = s0 + s1 + s2 + s3;
    __syncthreads();
    for (int off = 1; off < 1024; off <<= 1) {
      int v = part[tid];
      int add = (tid + off < 1024) ? part[tid + off] : 0;
      __syncthreads();
      part[tid] = v + add;
      __syncthreads();
    }
    int sufChunk = part[tid];
    int sufNext = (tid < 1023) ? part[tid + 1] : 0;
    if (sufNext < k && sufChunk >= k) {
      int run = sufNext;
      int b;
      run += s3;
      if (run >= k) b = b0 + 3;
      else {
        run += s2;
        if (run >= k) b = b0 + 2;
        else {
          run += s1;
          b = (run >= k) ? b0 + 1 : b0;
        }
      }
      sT = ((unsigned)b) << 20;
    }
  }
  __syncthreads();
  unsigned T = sT;
  __shared__ unsigned keys[1024];
  __shared__ int idxs[1024];
  __shared__ int cnt;
  if (tid == 0) cnt = 0;
  keys[tid] = 0u;
  idxs[tid] = 0x7fffffff;
  __syncthreads();
  for (int i = tid; i < n; i += 1024) {
    unsigned key = f2key(score[i]);
    if (key >= T) {
      int p = atomicAdd(&cnt, 1);
      if (p < 1024) { keys[p] = key; idxs[p] = i; }
    }
  }
  __syncthreads();
  for (int size = 2; size <= 1024; size <<= 1) {
    for (int stride = size >> 1; stride > 0; stride >>= 1) {
      int j = tid ^ stride;
      if (j > tid) {
        unsigned ka = keys[tid], kb = keys[j];
        int ia = idxs[tid], ib = idxs[j];
        bool aBefore = (ka > kb) || (ka == kb && ia < ib);
        bool up = ((tid & size) == 0);
        if (aBefore != up) {
          keys[tid] = kb; keys[j] = ka;
          idxs[tid] = ib; idxs[j] = ia;
        }
      }
      __syncthreads();
    }
  }
  if (tid < k) {
    int idx = idxs[tid];
    perm[tid] = idx;
    tts[tid] = tanhf(score[idx]);
  }
}

// GRU step with x_tilde computed inline (row i = x[perm[i]] * tts[i]);
// writes evolved W TRANSPOSED as bf16: WevoT[n*256 + k] = bf16(W[k][n])
__global__ __launch_bounds__(256) void gru_kernel(const float* __restrict__ x,
                                                  const int* __restrict__ perm,
                                                  const float* __restrict__ tts,
                                                  const float* __restrict__ Wi,
                                                  const float* __restrict__ W_ih,
                                                  const float* __restrict__ W_hh,
                                                  const float* __restrict__ b_ih,
                                                  const float* __restrict__ b_hh,
                                                  unsigned short* __restrict__ WevoT) {
  int i = blockIdx.x, j = threadIdx.x;  // i = k-row of W, j = n-col
  __shared__ float sx[256], sh[256];
  sx[j] = x[(size_t)perm[i] * 256 + j] * tts[i];
  sh[j] = Wi[i * 256 + j];
  __syncthreads();
  float gi[3], gh[3];
#pragma unroll
  for (int g = 0; g < 3; ++g) {
    int row = g * 256 + j;
    const float4* wi4 = (const float4*)(W_ih + (size_t)row * 256);
    const float4* wh4 = (const float4*)(W_hh + (size_t)row * 256);
    float si = 0.f, s2 = 0.f;
    for (int k4 = 0; k4 < 64; ++k4) {
      float4 wv = wi4[k4];
      float4 hv = wh4[k4];
      int k = k4 * 4;
      si += sx[k] * wv.x + sx[k + 1] * wv.y + sx[k + 2] * wv.z + sx[k + 3] * wv.w;
      s2 += sh[k] * hv.x + sh[k + 1] * hv.y + sh[k + 2] * hv.z + sh[k + 3] * hv.w;
    }
    gi[g] = si + b_ih[row];
    gh[g] = s2 + b_hh[row];
  }
  float r = 1.f / (1.f + expf(-(gi[0] + gh[0])));
  float z = 1.f / (1.f + expf(-(gi[1] + gh[1])));
  float nn = tanhf(gi[2] + r * gh[2]);
  float w = (1.f - z) * nn + z * sh[j];
  WevoT[(size_t)j * 256 + i] = f2bf(w);
}

// lin1_w [256][512] -> WA/WB bf16 each [256][256] at [n][k] (= B^T layout)
__global__ __launch_bounds__(256) void lin1_cast_kernel(const float* __restrict__ lin1,
                                                        unsigned short* __restrict__ WA,
                                                        unsigned short* __restrict__ WB) {
  int idx = blockIdx.x * 256 + threadIdx.x;  // 131072 total
  int n = idx >> 9, k = idx & 511;
  unsigned short h = f2bf(lin1[idx]);
  if (k < 256)
    WA[n * 256 + k] = h;
  else
    WB[n * 256 + (k - 256)] = h;
}

// ---------------------------------------------------------------------------
// Pure-bf16 MFMA GEMM: C[M,256] = A[M,256] @ B[256,256], bf16 in/out, fp32 acc.
// A row-major bf16; B as B^T rows (BT[n][k]). Layouts HW-verified (R3/R4).
// ---------------------------------------------------------------------------
__global__ __launch_bounds__(256) void mfma_gemm_bf16(const unsigned short* __restrict__ A,
                                                      const unsigned short* __restrict__ BT,
                                                      unsigned short* __restrict__ Cout, int M) {
  int tid = threadIdx.x;
  int wave = tid >> 6, lane = tid & 63;
  int quad = lane >> 4, r16 = lane & 15;
  int n0 = wave * 64;
  int mbase = blockIdx.x * 64;

  f32x4 acc[4][4];
#pragma unroll
  for (int i = 0; i < 4; ++i)
#pragma unroll
    for (int j = 0; j < 4; ++j) acc[i][j] = (f32x4){0.f, 0.f, 0.f, 0.f};

  for (int k0 = 0; k0 < 256; k0 += 32) {
    int koff = k0 + quad * 8;
    bf16x8 af[4], bf[4];
#pragma unroll
    for (int mt = 0; mt < 4; ++mt) {
      int row = mbase + mt * 16 + r16;
      row = row < M ? row : M - 1;
      af[mt] = *(const bf16x8*)(A + (size_t)row * 256 + koff);
    }
#pragma unroll
    for (int nt = 0; nt < 4; ++nt) {
      int nrow = n0 + nt * 16 + r16;
      bf[nt] = *(const bf16x8*)(BT + (size_t)nrow * 256 + koff);
    }
#pragma unroll
    for (int mt = 0; mt < 4; ++mt)
#pragma unroll
      for (int nt = 0; nt < 4; ++nt)
        acc[mt][nt] = __builtin_amdgcn_mfma_f32_16x16x32_bf16(af[mt], bf[nt], acc[mt][nt], 0, 0, 0);
  }
#pragma unroll
  for (int mt = 0; mt < 4; ++mt) {
#pragma unroll
    for (int rr = 0; rr < 4; ++rr) {
      int grow = mbase + mt * 16 + quad * 4 + rr;
      if (grow < M) {
#pragma unroll
        for (int nt = 0; nt < 4; ++nt)
          Cout[(size_t)grow * 256 + n0 + nt * 16 + r16] = f2bf(acc[mt][nt][rr]);
      }
    }
  }
}

// Dual variant: reads A once, produces C1 = A@B1 and C2 = A@B2.
__global__ __launch_bounds__(256) void mfma_gemm_bf16_dual(const unsigned short* __restrict__ A,
                                                           const unsigned short* __restrict__ BT1,
                                                           const unsigned short* __restrict__ BT2,
                                                           unsigned short* __restrict__ C1,
                                                           unsigned short* __restrict__ C2, int M) {
  int tid = threadIdx.x;
  int wave = tid >> 6, lane = tid & 63;
  int quad = lane >> 4, r16 = lane & 15;
  int n0 = wave * 64;
  int mbase = blockIdx.x * 64;

  f32x4 acc1[4][4], acc2[4][4];
#pragma unroll
  for (int i = 0; i < 4; ++i)
#pragma unroll
    for (int j = 0; j < 4; ++j) {
      acc1[i][j] = (f32x4){0.f, 0.f, 0.f, 0.f};
      acc2[i][j] = (f32x4){0.f, 0.f, 0.f, 0.f};
    }

  for (int k0 = 0; k0 < 256; k0 += 32) {
    int koff = k0 + quad * 8;
    bf16x8 af[4], b1[4], b2[4];
#pragma unroll
    for (int mt = 0; mt < 4; ++mt) {
      int row = mbase + mt * 16 + r16;
      row = row < M ? row : M - 1;
      af[mt] = *(const bf16x8*)(A + (size_t)row * 256 + koff);
    }
#pragma unroll
    for (int nt = 0; nt < 4; ++nt) {
      int nrow = n0 + nt * 16 + r16;
      b1[nt] = *(const bf16x8*)(BT1 + (size_t)nrow * 256 + koff);
      b2[nt] = *(const bf16x8*)(BT2 + (size_t)nrow * 256 + koff);
    }
#pragma unroll
    for (int mt = 0; mt < 4; ++mt)
#pragma unroll
      for (int nt = 0; nt < 4; ++nt) {
        acc1[mt][nt] = __builtin_amdgcn_mfma_f32_16x16x32_bf16(af[mt], b1[nt], acc1[mt][nt], 0, 0, 0);
        acc2[mt][nt] = __builtin_amdgcn_mfma_f32_16x16x32_bf16(af[mt], b2[nt], acc2[mt][nt], 0, 0, 0);
      }
  }
#pragma unroll
  for (int mt = 0; mt < 4; ++mt) {
#pragma unroll
    for (int rr = 0; rr < 4; ++rr) {
      int grow = mbase + mt * 16 + quad * 4 + rr;
      if (grow < M) {
#pragma unroll
        for (int nt = 0; nt < 4; ++nt) {
          size_t o = (size_t)grow * 256 + n0 + nt * 16 + r16;
          C1[o] = f2bf(acc1[mt][nt][rr]);
          C2[o] = f2bf(acc2[mt][nt][rr]);
        }
      }
    }
  }
}

// ---- two-phase bucket sort for both CSRs -----------------------------------

// phase 0: bucket histogram (391 bins) for conv-dst and decoder-src
__global__ __launch_bounds__(256) void bucket_hist_kernel(const int* __restrict__ ei,
                                                          const int* __restrict__ ewi,
                                                          int* __restrict__ bcnt1,
                                                          int* __restrict__ bcnt2, int E) {
  __shared__ int c1[512], c2[512];
  int tid = threadIdx.x;
  for (int i = tid; i < 512; i += 256) { c1[i] = 0; c2[i] = 0; }
  __syncthreads();
  int idx = blockIdx.x * 256 + tid;
  int stride = gridDim.x * 256;
  for (int e = idx; e < E; e += stride) {
    atomicAdd(&c1[ei[E + e] >> WSHIFT], 1);
    atomicAdd(&c2[ewi[e] >> WSHIFT], 1);
  }
  __syncthreads();
  for (int i = tid; i < NBUCK; i += 256) {
    if (c1[i]) atomicAdd(&bcnt1[i], c1[i]);
    if (c2[i]) atomicAdd(&bcnt2[i], c2[i]);
  }
}

// phase 0b: scan bucket counts -> bases + cursors; also rowp[N] = E
__global__ __launch_bounds__(512) void bucket_scan_kernel(const int* __restrict__ bcnt1,
                                                          const int* __restrict__ bcnt2,
                                                          int* __restrict__ bbase1,
                                                          int* __restrict__ bbase2,
                                                          int* __restrict__ gcur1,
                                                          int* __restrict__ gcur2,
                                                          int* __restrict__ rowp1,
                                                          int* __restrict__ rowp2, int N, int E) {
  __shared__ int ss[512];
  int tid = threadIdx.x;
  // CSR 1
  int v = (tid < NBUCK) ? bcnt1[tid] : 0;
  ss[tid] = v;
  __syncthreads();
  for (int off = 1; off < 512; off <<= 1) {
    int a = ss[tid];
    int b = (tid >= off) ? ss[tid - off] : 0;
    __syncthreads();
    ss[tid] = a + b;
    __syncthreads();
  }
  int excl = ss[tid] - v;
  if (tid < NBUCK) { bbase1[tid] = excl; gcur1[tid] = excl; }
  if (tid == NBUCK - 1) bbase1[NBUCK] = excl + v;
  __syncthreads();
  // CSR 2
  v = (tid < NBUCK) ? bcnt2[tid] : 0;
  ss[tid] = v;
  __syncthreads();
  for (int off = 1; off < 512; off <<= 1) {
    int a = ss[tid];
    int b = (tid >= off) ? ss[tid - off] : 0;
    __syncthreads();
    ss[tid] = a + b;
    __syncthreads();
  }
  excl = ss[tid] - v;
  if (tid < NBUCK) { bbase2[tid] = excl; gcur2[tid] = excl; }
  if (tid == NBUCK - 1) bbase2[NBUCK] = excl + v;
  if (tid == 0) { rowp1[N] = E; rowp2[N] = E; }
}

// phase 1 (both CSRs): tile-ranked scatter into bucket staging. 2048 edges/blk.
// stage1.x = src | (dstLocal<<16), stage1.y = attr bits (src < 65536)
// stage2.x = dst | (srcLocal<<16), stage2.y = edge_id
__global__ __launch_bounds__(256) void p1_kernel(const int* __restrict__ ei,
                                                 const float* __restrict__ attr,
                                                 const int* __restrict__ ewi,
                                                 int* __restrict__ gcur1,
                                                 int* __restrict__ gcur2,
                                                 int2* __restrict__ stage1,
                                                 int2* __restrict__ stage2, int E) {
  __shared__ int cnt1[512], cur1[512], cnt2[512], cur2[512];
  int tid = threadIdx.x;
  int base = blockIdx.x * 2048;
  for (int i = tid; i < 512; i += 256) { cnt1[i] = 0; cnt2[i] = 0; }
  __syncthreads();
  int bk1[8], bk2[8];
  int2 pl1[8], pl2[8];
#pragma unroll
  for (int i = 0; i < 8; ++i) {
    int e = base + i * 256 + tid;
    bk1[i] = -1;
    bk2[i] = -1;
    if (e < E) {
      int d = ei[E + e], s = ei[e];
      bk1[i] = d >> WSHIFT;
      pl1[i] = make_int2(s | ((d & WMASK) << 16), __float_as_int(attr[e]));
      atomicAdd(&cnt1[bk1[i]], 1);
      int s2 = ewi[e], d2 = ewi[E + e];
      bk2[i] = s2 >> WSHIFT;
      pl2[i] = make_int2(d2 | ((s2 & WMASK) << 16), e);
      atomicAdd(&cnt2[bk2[i]], 1);
    }
  }
  __syncthreads();
  for (int i = tid; i < NBUCK; i += 256) {
    int c = cnt1[i];
    cur1[i] = c ? atomicAdd(&gcur1[i], c) : 0;
    c = cnt2[i];
    cur2[i] = c ? atomicAdd(&gcur2[i], c) : 0;
  }
  __syncthreads();
#pragma unroll
  for (int i = 0; i < 8; ++i) {
    if (bk1[i] >= 0) {
      int pos = atomicAdd(&cur1[bk1[i]], 1);
      stage1[pos] = pl1[i];
      int pos2 = atomicAdd(&cur2[bk2[i]], 1);
      stage2[pos2] = pl2[i];
    }
  }
}

// phase 2 (both CSRs, gridDim.x = 2*NBUCK): one block per bucket.
// LDS 128-bin node histogram (+deg for conv), scan, node-ordered CSR write.
__global__ __launch_bounds__(256) void p2_kernel(const int2* __restrict__ stage1,
                                                 const int* __restrict__ bbase1,
                                                 int2* __restrict__ esv,
                                                 int* __restrict__ rowp1,
                                                 float* __restrict__ dinv,
                                                 const int2* __restrict__ stage2,
                                                 const int* __restrict__ bbase2,
                                                 int2* __restrict__ eto,
                                                 int* __restrict__ rowp2, int N) {
  __shared__ int cnt[128];
  __shared__ float degs[128];
  __shared__ int pref[128];
  __shared__ int ssc[128];
  int tid = threadIdx.x;
  bool isConv = blockIdx.x < NBUCK;
  int b = isConv ? blockIdx.x : blockIdx.x - NBUCK;
  const int2* stage = isConv ? stage1 : stage2;
  const int* bbase = isConv ? bbase1 : bbase2;
  int beg = bbase[b], end = bbase[b + 1];
  int node0 = b << WSHIFT;
  if (tid < 128) { cnt[tid] = 0; degs[tid] = 0.f; }
  __syncthreads();
  for (int j = beg + tid; j < end; j += 256) {
    int2 p = stage[j];
    int loc = p.x >> 16;
    atomicAdd(&cnt[loc], 1);
    if (isConv) atomicAdd(&degs[loc], __int_as_float(p.y));
  }
  __syncthreads();
  int v = (tid < 128) ? cnt[tid] : 0;
  if (tid < 128) ssc[tid] = v;
  __syncthreads();
  for (int off = 1; off < 128; off <<= 1) {
    int a = (tid < 128) ? ssc[tid] : 0;
    int add = (tid < 128 && tid >= off) ? ssc[tid - off] : 0;
    __syncthreads();
    if (tid < 128) ssc[tid] = a + add;
    __syncthreads();
  }
  if (tid < 128) {
    int excl = ssc[tid] - v;
    pref[tid] = excl;
    int node = node0 + tid;
    if (node < N) {
      if (isConv) {
        rowp1[node] = beg + excl;
        float d = degs[tid];
        dinv[node] = d > 0.f ? 1.f / sqrtf(d) : 0.f;
      } else {
        rowp2[node] = beg + excl;
      }
    }
  }
  __syncthreads();
  int2* outb = isConv ? esv : eto;
  for (int j = beg + tid; j < end; j += 256) {
    int2 p = stage[j];
    int loc = p.x >> 16;
    int pos = beg + atomicAdd(&pref[loc], 1);
    outb[pos] = make_int2(p.x & 0xFFFF, p.y);
  }
}

// one wave per dst node, 8-lane decomposition: 8 lanes/edge x 8 edges/round.
// Lane g=lane&7 owns channels [g*32, g*32+32); slot q=lane>>3 handles edge jb+q.
__global__ __launch_bounds__(256) void gcn_gather(const unsigned short* __restrict__ xw,
                                                  const int* __restrict__ row_ptr,
                                                  const int2* __restrict__ esv,
                                                  const float* __restrict__ dinv,
                                                  unsigned short* __restrict__ ne, int N) {
  int node = blockIdx.x * 4 + (threadIdx.x >> 6);
  int lane = threadIdx.x & 63;
  int g = lane & 7, q = lane >> 3;
  if (node >= N) return;
  int beg = row_ptr[node], end = row_ptr[node + 1];
  float acc[32];
#pragma unroll
  for (int c = 0; c < 32; ++c) acc[c] = 0.f;
  const unsigned short* xb = xw + g * 32;
  if (beg < end) {
    int e0 = beg + q;
    int2 m0 = (e0 < end) ? esv[e0] : make_int2(0, 0);
    float v0 = (e0 < end) ? dinv[m0.x] * __int_as_float(m0.y) : 0.f;
    u16x8 r0[4];
#pragma unroll
    for (int h = 0; h < 4; ++h) r0[h] = *(const u16x8*)(xb + (size_t)m0.x * 256 + h * 8);
    for (int jb = beg; jb < end; jb += 8) {
      float v1 = 0.f;
      u16x8 r1[4];
#pragma unroll
      for (int h = 0; h < 4; ++h) r1[h] = r0[h];
      if (jb + 8 < end) {
        int e1 = jb + 8 + q;
        int2 m1 = (e1 < end) ? esv[e1] : make_int2(0, 0);
        v1 = (e1 < end) ? dinv[m1.x] * __int_as_float(m1.y) : 0.f;
#pragma unroll
        for (int h = 0; h < 4; ++h) r1[h] = *(const u16x8*)(xb + (size_t)m1.x * 256 + h * 8);
      }
#pragma unroll
      for (int h = 0; h < 4; ++h)
#pragma unroll
        for (int c = 0; c < 8; ++c) acc[h * 8 + c] += bf2f(r0[h][c]) * v0;
      v0 = v1;
#pragma unroll
      for (int h = 0; h < 4; ++h) r0[h] = r1[h];
    }
  }
  // cross-slot combine (8 partials over the same 32 channels)
#pragma unroll
  for (int c = 0; c < 32; ++c) {
    acc[c] += __shfl_xor(acc[c], 8, 64);
    acc[c] += __shfl_xor(acc[c], 16, 64);
    acc[c] += __shfl_xor(acc[c], 32, 64);
  }
  if (q == 0) {
    float dd = dinv[node];
#pragma unroll
    for (int h = 0; h < 4; ++h) {
      u16x8 o;
#pragma unroll
      for (int c = 0; c < 8; ++c) o[c] = f2bf(acc[h * 8 + c] * dd);
      *(u16x8*)(ne + (size_t)node * 256 + g * 32 + h * 8) = o;
    }
  }
}

// decode grouped by src, 8-lane decomposition: 8 lanes/edge x 8 edges/round.
// A[s]+b1 and w2 register-resident (32 ch/lane); 3-step reduce across g.
__global__ __launch_bounds__(256) void edge_decode_csr(const unsigned short* __restrict__ A,
                                                       const unsigned short* __restrict__ Bm,
                                                       const int* __restrict__ row_ptr,
                                                       const int2* __restrict__ eto,
                                                       const float* __restrict__ b1,
                                                       const float* __restrict__ w2,
                                                       const float* __restrict__ b2,
                                                       float* __restrict__ out, int N) {
  int node = blockIdx.x * 4 + (threadIdx.x >> 6);
  int lane = threadIdx.x & 63;
  int g = lane & 7, q = lane >> 3;
  if (node >= N) return;
  int beg = row_ptr[node], end = row_ptr[node + 1];
  if (beg >= end) return;
  float a[32], w[32];
  {
    const float4* bp = (const float4*)(b1 + g * 32);
    const float4* wp = (const float4*)(w2 + g * 32);
#pragma unroll
    for (int h = 0; h < 4; ++h) {
      u16x8 av = *(const u16x8*)(A + (size_t)node * 256 + g * 32 + h * 8);
      float4 b0 = bp[h * 2], b1v = bp[h * 2 + 1];
      float4 w0 = wp[h * 2], w1v = wp[h * 2 + 1];
      a[h * 8 + 0] = bf2f(av[0]) + b0.x;
      a[h * 8 + 1] = bf2f(av[1]) + b0.y;
      a[h * 8 + 2] = bf2f(av[2]) + b0.z;
      a[h * 8 + 3] = bf2f(av[3]) + b0.w;
      a[h * 8 + 4] = bf2f(av[4]) + b1v.x;
      a[h * 8 + 5] = bf2f(av[5]) + b1v.y;
      a[h * 8 + 6] = bf2f(av[6]) + b1v.z;
      a[h * 8 + 7] = bf2f(av[7]) + b1v.w;
      w[h * 8 + 0] = w0.x;
      w[h * 8 + 1] = w0.y;
      w[h * 8 + 2] = w0.z;
      w[h * 8 + 3] = w0.w;
      w[h * 8 + 4] = w1v.x;
      w[h * 8 + 5] = w1v.y;
      w[h * 8 + 6] = w1v.z;
      w[h * 8 + 7] = w1v.w;
    }
  }
  float base = b2[0];
  const unsigned short* Bb = Bm + g * 32;
  int e0 = beg + q;
  int2 m0 = (e0 < end) ? eto[e0] : make_int2(0, -1);
  u16x8 r0[4];
#pragma unroll
  for (int h = 0; h < 4; ++h) r0[h] = *(const u16x8*)(Bb + (size_t)m0.x * 256 + h * 8);
  for (int jb = beg; jb < end; jb += 8) {
    int2 m1 = make_int2(0, -1);
    u16x8 r1[4];
#pragma unroll
    for (int h = 0; h < 4; ++h) r1[h] = r0[h];
    if (jb + 8 < end) {
      int e1 = jb + 8 + q;
      m1 = (e1 < end) ? eto[e1] : make_int2(0, -1);
#pragma unroll
      for (int h = 0; h < 4; ++h) r1[h] = *(const u16x8*)(Bb + (size_t)m1.x * 256 + h * 8);
    }
    float s = 0.f;
#pragma unroll
    for (int h = 0; h < 4; ++h)
#pragma unroll
      for (int c = 0; c < 8; ++c)
        s += fmaxf(a[h * 8 + c] + bf2f(r0[h][c]), 0.f) * w[h * 8 + c];
    s += __shfl_xor(s, 1, 64);
    s += __shfl_xor(s, 2, 64);
    s += __shfl_xor(s, 4, 64);
    if (g == 0 && m0.y >= 0) out[m0.y] = s + base;
    m0 = m1;
#pragma unroll
    for (int h = 0; h < 4; ++h) r0[h] = r1[h];
  }
}

extern "C" void kernel_launch(void* const* d_in, const int* in_sizes, int n_in,
                              void* d_out, int out_size, void* d_ws, size_t ws_size,
                              hipStream_t stream) {
  const float* x      = (const float*)d_in[0];
  const int*   ei     = (const int*)d_in[1];
  const float* attr   = (const float*)d_in[2];
  const int*   ewi    = (const int*)d_in[3];
  const float* p_pool = (const float*)d_in[4];
  const float* W_ih   = (const float*)d_in[5];
  const float* W_hh   = (const float*)d_in[6];
  const float* b_ih   = (const float*)d_in[7];
  const float* b_hh   = (const float*)d_in[8];
  const float* W_init = (const float*)d_in[9];
  const float* lin1_w = (const float*)d_in[10];
  const float* lin1_b = (const float*)d_in[11];
  const float* lin2_w = (const float*)d_in[12];
  const float* lin2_b = (const float*)d_in[13];
  float* out = (float*)d_out;

  const int C = 256;
  const int N = in_sizes[0] / C;   // 50000
  const int E = in_sizes[2];       // 800000

  // ---- workspace layout (256B aligned) ----
  char* ws = (char*)d_ws;
  size_t off = 0;
  auto alloc = [&](size_t bytes) {
    size_t o = off;
    off = (off + bytes + 255) & ~(size_t)255;
    return o;
  };
  float*          score  = (float*)(ws + alloc((size_t)N * 4));
  int*            perm   = (int*)(ws + alloc(C * 4));
  float*          tts    = (float*)(ws + alloc(C * 4));
  unsigned short* WevoT  = (unsigned short*)(ws + alloc((size_t)C * C * 2));
  unsigned short* WA     = (unsigned short*)(ws + alloc((size_t)C * C * 2));
  unsigned short* WB     = (unsigned short*)(ws + alloc((size_t)C * C * 2));
  // contiguous zero region: ghist | bcnt1 | bcnt2
  int   zeroInts = 4096 + 512 + 512;
  char* zbase    = ws + alloc((size_t)zeroInts * 4);
  int* ghist = (int*)zbase;
  int* bcnt1 = (int*)(zbase + 4096 * 4);
  int* bcnt2 = (int*)(zbase + 4096 * 4 + 512 * 4);
  int*            bbase1 = (int*)(ws + alloc((NBUCK + 1) * 4));
  int*            bbase2 = (int*)(ws + alloc((NBUCK + 1) * 4));
  int*            gcur1  = (int*)(ws + alloc(512 * 4));
  int*            gcur2  = (int*)(ws + alloc(512 * 4));
  float*          dinv   = (float*)(ws + alloc((size_t)N * 4));
  int*            rowp1  = (int*)(ws + alloc((size_t)(N + 1) * 4));
  int*            rowp2  = (int*)(ws + alloc((size_t)(N + 1) * 4));
  int2*           stage1 = (int2*)(ws + alloc((size_t)E * 8));
  int2*           stage2 = (int2*)(ws + alloc((size_t)E * 8));
  int2*           esv    = (int2*)(ws + alloc((size_t)E * 8));
  int2*           eto    = (int2*)(ws + alloc((size_t)E * 8));
  unsigned short* xh     = (unsigned short*)(ws + alloc((size_t)N * C * 2));
  unsigned short* xwh    = (unsigned short*)(ws + alloc((size_t)N * C * 2));
  unsigned short* Bbf    = (unsigned short*)(ws + alloc((size_t)N * C * 2));
  // aliases (stream-ordered producers/consumers):
  unsigned short* ne  = xh;   // xh dead after GEMM1
  unsigned short* Abf = xwh;  // xwh dead after gather

  // 0) zero ghist/bcnt in one tiny launch
  zero_kernel<<<(zeroInts / 4 + 255) / 256, 256, 0, stream>>>((float4*)zbase, zeroInts / 4);

  // 1) score (+||p||) + bf16 cast of x + score histogram
  score_cast_kernel<<<(N + 3) / 4, 256, 0, stream>>>(x, p_pool, score, xh, ghist, N);

  // 2) exact top-256: fused select+collect+sort
  topk_kernel<<<1, 1024, 0, stream>>>(score, N, C, ghist, perm, tts);

  // 3+4) GRU (x_tilde inline) -> evolved W (transposed bf16)
  gru_kernel<<<C, C, 0, stream>>>(x, perm, tts, W_init, W_ih, W_hh, b_ih, b_hh, WevoT);

  // 5) xw = x @ Wevo (bf16 MFMA, bf16 out)
  mfma_gemm_bf16<<<(N + 63) / 64, 256, 0, stream>>>(xh, WevoT, xwh, N);

  // 6) two-phase bucket sort for both CSRs (also produces deg/dinv in p2)
  bucket_hist_kernel<<<256, 256, 0, stream>>>(ei, ewi, bcnt1, bcnt2, E);
  bucket_scan_kernel<<<1, 512, 0, stream>>>(bcnt1, bcnt2, bbase1, bbase2, gcur1, gcur2,
                                            rowp1, rowp2, N, E);
  p1_kernel<<<(E + 2047) / 2048, 256, 0, stream>>>(ei, attr, ewi, gcur1, gcur2,
                                                   stage1, stage2, E);
  p2_kernel<<<2 * NBUCK, 256, 0, stream>>>(stage1, bbase1, esv, rowp1, dinv,
                                           stage2, bbase2, eto, rowp2, N);

  // 7) gather (8-lane decomposition)
  gcn_gather<<<(N + 3) / 4, 256, 0, stream>>>(xwh, rowp1, esv, dinv, ne, N);

  // 8) decoder projections fused (lin1_w rows ARE the B^T layout)
  lin1_cast_kernel<<<(2 * C * C) / 256, 256, 0, stream>>>(lin1_w, WA, WB);
  mfma_gemm_bf16_dual<<<(N + 63) / 64, 256, 0, stream>>>(ne, WA, WB, Abf, Bbf, N);

  // 9) edge decode (8-lane decomposition)
  edge_decode_csr<<<(N + 3) / 4, 256, 0, stream>>>(Abf, Bbf, rowp2, eto,
                                                   lin1_b, lin2_w, lin2_b, out, N);
}

// Round 10
// 591.921 us; speedup vs baseline: 1.2387x; 1.2387x over previous
//
#include <hip/hip_runtime.h>
#include <hip/hip_bf16.h>
#include <math.h>

// ---------------------------------------------------------------------------
// EvolveGCNH + GCNConv + EdgeDecoder.
// R1: atomic scatter -> dst-CSR register gather (3574 -> 1223 us).
// R3/R4: bf16 MFMA GEMMs, bf16 operands, src-CSR grouped decode.
// R5: parallel top-k, merged CSR builds, dual GEMM (962 us).
// R7: two-phase bucket sort for both CSRs (609 us).
// R8: quad decomposition gather/decode + kernel fusion (522 us).
// R9: REGRESSED (733 us): (a) score-histogram as global atomics -> hot-bin
//     cross-XCD serialization (174 us); (b) 391 buckets x 2048-edge tiles ->
//     42 B runs < cache line -> partial-line write amp again.
// R10: revert sort path to 98 buckets / 4096-edge tiles + separate
//      LDS-aggregated hist12; KEEP 8-lane gather/decode (8 edges in flight,
//      3-step reduce) and merged 196-block p2.
// ---------------------------------------------------------------------------

typedef __attribute__((ext_vector_type(8))) short bf16x8;
typedef __attribute__((ext_vector_type(8))) unsigned short u16x8;
typedef __attribute__((ext_vector_type(4))) float f32x4;

#define WSHIFT 9              // 512 nodes per bucket
#define WMASK 511
#define NBUCK 98              // ceil(50000/512)

__device__ __forceinline__ unsigned f2key(float f) {
  unsigned u = __float_as_uint(f);
  return (u & 0x80000000u) ? ~u : (u | 0x80000000u);
}

// round-to-nearest-even fp32 -> bf16 bits
__device__ __forceinline__ unsigned short f2bf(float f) {
  unsigned u = __float_as_uint(f);
  unsigned r = u + 0x7fffu + ((u >> 16) & 1u);
  return (unsigned short)(r >> 16);
}
__device__ __forceinline__ float bf2f(unsigned short h) {
  return __uint_as_float((unsigned)h << 16);
}

__global__ void zero_kernel(float4* __restrict__ p, int n4) {
  int i = blockIdx.x * blockDim.x + threadIdx.x;
  if (i < n4) p[i] = make_float4(0.f, 0.f, 0.f, 0.f);
}

// score (incl. ||p||) + bf16 cast of x in one pass (x read once)
__global__ __launch_bounds__(256) void score_cast_kernel(const float* __restrict__ x,
                                                         const float* __restrict__ p,
                                                         float* __restrict__ score,
                                                         unsigned short* __restrict__ xh, int N) {
  int node = blockIdx.x * 4 + (threadIdx.x >> 6);
  int lane = threadIdx.x & 63;
  if (node >= N) return;
  float4 xv = ((const float4*)(x + (size_t)node * 256))[lane];
  ushort4 hv;
  hv.x = f2bf(xv.x);
  hv.y = f2bf(xv.y);
  hv.z = f2bf(xv.z);
  hv.w = f2bf(xv.w);
  ((ushort4*)(xh + (size_t)node * 256))[lane] = hv;
  float4 pv = ((const float4*)p)[lane];
  float s = xv.x * pv.x + xv.y * pv.y + xv.z * pv.z + xv.w * pv.w;
  float sp = pv.x * pv.x + pv.y * pv.y + pv.z * pv.z + pv.w * pv.w;
#pragma unroll
  for (int off = 32; off > 0; off >>= 1) {
    s += __shfl_down(s, off, 64);
    sp += __shfl_down(sp, off, 64);
  }
  if (lane == 0) score[node] = s / sqrtf(sp);
}

// grid-wide histogram of the top 12 key bits (4096 bins), LDS-aggregated
__global__ __launch_bounds__(256) void hist12_kernel(const float* __restrict__ score, int n,
                                                     int* __restrict__ gh) {
  __shared__ int lh[4096];
  int tid = threadIdx.x;
  for (int i = tid; i < 4096; i += 256) lh[i] = 0;
  __syncthreads();
  int idx = blockIdx.x * 256 + tid;
  int stride = gridDim.x * 256;
  for (int i = idx; i < n; i += stride) {
    unsigned key = f2key(score[i]);
    atomicAdd(&lh[key >> 20], 1);
  }
  __syncthreads();
  for (int i = tid; i < 4096; i += 256) {
    int v = lh[i];
    if (v) atomicAdd(&gh[i], v);
  }
}

// select (suffix-scan over 4096-bin histogram -> bin-floor threshold) fused
// with collect + bitonic sort (key desc, idx asc) -> perm[k], tanh(score).
__global__ __launch_bounds__(1024) void topk_kernel(const float* __restrict__ score, int n, int k,
                                                    const int* __restrict__ gh,
                                                    int* __restrict__ perm,
                                                    float* __restrict__ tts) {
  __shared__ int part[1024];
  __shared__ unsigned sT;
  int tid = threadIdx.x;
  {
    int b0 = tid * 4;
    int s0 = gh[b0], s1 = gh[b0 + 1], s2 = gh[b0 + 2], s3 = gh[b0 + 3];
    part[tid] = s0 + s1 + s2 + s3;
    __syncthreads();
    for (int off = 1; off < 1024; off <<= 1) {
      int v = part[tid];
      int add = (tid + off < 1024) ? part[tid + off] : 0;
      __syncthreads();
      part[tid] = v + add;
      __syncthreads();
    }
    int sufChunk = part[tid];
    int sufNext = (tid < 1023) ? part[tid + 1] : 0;
    if (sufNext < k && sufChunk >= k) {
      int run = sufNext;
      int b;
      run += s3;
      if (run >= k) b = b0 + 3;
      else {
        run += s2;
        if (run >= k) b = b0 + 2;
        else {
          run += s1;
          b = (run >= k) ? b0 + 1 : b0;
        }
      }
      sT = ((unsigned)b) << 20;
    }
  }
  __syncthreads();
  unsigned T = sT;
  __shared__ unsigned keys[1024];
  __shared__ int idxs[1024];
  __shared__ int cnt;
  if (tid == 0) cnt = 0;
  keys[tid] = 0u;
  idxs[tid] = 0x7fffffff;
  __syncthreads();
  for (int i = tid; i < n; i += 1024) {
    unsigned key = f2key(score[i]);
    if (key >= T) {
      int p = atomicAdd(&cnt, 1);
      if (p < 1024) { keys[p] = key; idxs[p] = i; }
    }
  }
  __syncthreads();
  for (int size = 2; size <= 1024; size <<= 1) {
    for (int stride = size >> 1; stride > 0; stride >>= 1) {
      int j = tid ^ stride;
      if (j > tid) {
        unsigned ka = keys[tid], kb = keys[j];
        int ia = idxs[tid], ib = idxs[j];
        bool aBefore = (ka > kb) || (ka == kb && ia < ib);
        bool up = ((tid & size) == 0);
        if (aBefore != up) {
          keys[tid] = kb; keys[j] = ka;
          idxs[tid] = ib; idxs[j] = ia;
        }
      }
      __syncthreads();
    }
  }
  if (tid < k) {
    int idx = idxs[tid];
    perm[tid] = idx;
    tts[tid] = tanhf(score[idx]);
  }
}

// GRU step with x_tilde computed inline (row i = x[perm[i]] * tts[i]);
// writes evolved W TRANSPOSED as bf16: WevoT[n*256 + k] = bf16(W[k][n])
__global__ __launch_bounds__(256) void gru_kernel(const float* __restrict__ x,
                                                  const int* __restrict__ perm,
                                                  const float* __restrict__ tts,
                                                  const float* __restrict__ Wi,
                                                  const float* __restrict__ W_ih,
                                                  const float* __restrict__ W_hh,
                                                  const float* __restrict__ b_ih,
                                                  const float* __restrict__ b_hh,
                                                  unsigned short* __restrict__ WevoT) {
  int i = blockIdx.x, j = threadIdx.x;  // i = k-row of W, j = n-col
  __shared__ float sx[256], sh[256];
  sx[j] = x[(size_t)perm[i] * 256 + j] * tts[i];
  sh[j] = Wi[i * 256 + j];
  __syncthreads();
  float gi[3], gh[3];
#pragma unroll
  for (int g = 0; g < 3; ++g) {
    int row = g * 256 + j;
    const float4* wi4 = (const float4*)(W_ih + (size_t)row * 256);
    const float4* wh4 = (const float4*)(W_hh + (size_t)row * 256);
    float si = 0.f, s2 = 0.f;
    for (int k4 = 0; k4 < 64; ++k4) {
      float4 wv = wi4[k4];
      float4 hv = wh4[k4];
      int k = k4 * 4;
      si += sx[k] * wv.x + sx[k + 1] * wv.y + sx[k + 2] * wv.z + sx[k + 3] * wv.w;
      s2 += sh[k] * hv.x + sh[k + 1] * hv.y + sh[k + 2] * hv.z + sh[k + 3] * hv.w;
    }
    gi[g] = si + b_ih[row];
    gh[g] = s2 + b_hh[row];
  }
  float r = 1.f / (1.f + expf(-(gi[0] + gh[0])));
  float z = 1.f / (1.f + expf(-(gi[1] + gh[1])));
  float nn = tanhf(gi[2] + r * gh[2]);
  float w = (1.f - z) * nn + z * sh[j];
  WevoT[(size_t)j * 256 + i] = f2bf(w);
}

// lin1_w [256][512] -> WA/WB bf16 each [256][256] at [n][k] (= B^T layout)
__global__ __launch_bounds__(256) void lin1_cast_kernel(const float* __restrict__ lin1,
                                                        unsigned short* __restrict__ WA,
                                                        unsigned short* __restrict__ WB) {
  int idx = blockIdx.x * 256 + threadIdx.x;  // 131072 total
  int n = idx >> 9, k = idx & 511;
  unsigned short h = f2bf(lin1[idx]);
  if (k < 256)
    WA[n * 256 + k] = h;
  else
    WB[n * 256 + (k - 256)] = h;
}

// ---------------------------------------------------------------------------
// Pure-bf16 MFMA GEMM: C[M,256] = A[M,256] @ B[256,256], bf16 in/out, fp32 acc.
// A row-major bf16; B as B^T rows (BT[n][k]). Layouts HW-verified (R3/R4).
// ---------------------------------------------------------------------------
__global__ __launch_bounds__(256) void mfma_gemm_bf16(const unsigned short* __restrict__ A,
                                                      const unsigned short* __restrict__ BT,
                                                      unsigned short* __restrict__ Cout, int M) {
  int tid = threadIdx.x;
  int wave = tid >> 6, lane = tid & 63;
  int quad = lane >> 4, r16 = lane & 15;
  int n0 = wave * 64;
  int mbase = blockIdx.x * 64;

  f32x4 acc[4][4];
#pragma unroll
  for (int i = 0; i < 4; ++i)
#pragma unroll
    for (int j = 0; j < 4; ++j) acc[i][j] = (f32x4){0.f, 0.f, 0.f, 0.f};

  for (int k0 = 0; k0 < 256; k0 += 32) {
    int koff = k0 + quad * 8;
    bf16x8 af[4], bf[4];
#pragma unroll
    for (int mt = 0; mt < 4; ++mt) {
      int row = mbase + mt * 16 + r16;
      row = row < M ? row : M - 1;
      af[mt] = *(const bf16x8*)(A + (size_t)row * 256 + koff);
    }
#pragma unroll
    for (int nt = 0; nt < 4; ++nt) {
      int nrow = n0 + nt * 16 + r16;
      bf[nt] = *(const bf16x8*)(BT + (size_t)nrow * 256 + koff);
    }
#pragma unroll
    for (int mt = 0; mt < 4; ++mt)
#pragma unroll
      for (int nt = 0; nt < 4; ++nt)
        acc[mt][nt] = __builtin_amdgcn_mfma_f32_16x16x32_bf16(af[mt], bf[nt], acc[mt][nt], 0, 0, 0);
  }
#pragma unroll
  for (int mt = 0; mt < 4; ++mt) {
#pragma unroll
    for (int rr = 0; rr < 4; ++rr) {
      int grow = mbase + mt * 16 + quad * 4 + rr;
      if (grow < M) {
#pragma unroll
        for (int nt = 0; nt < 4; ++nt)
          Cout[(size_t)grow * 256 + n0 + nt * 16 + r16] = f2bf(acc[mt][nt][rr]);
      }
    }
  }
}

// Dual variant: reads A once, produces C1 = A@B1 and C2 = A@B2.
__global__ __launch_bounds__(256) void mfma_gemm_bf16_dual(const unsigned short* __restrict__ A,
                                                           const unsigned short* __restrict__ BT1,
                                                           const unsigned short* __restrict__ BT2,
                                                           unsigned short* __restrict__ C1,
                                                           unsigned short* __restrict__ C2, int M) {
  int tid = threadIdx.x;
  int wave = tid >> 6, lane = tid & 63;
  int quad = lane >> 4, r16 = lane & 15;
  int n0 = wave * 64;
  int mbase = blockIdx.x * 64;

  f32x4 acc1[4][4], acc2[4][4];
#pragma unroll
  for (int i = 0; i < 4; ++i)
#pragma unroll
    for (int j = 0; j < 4; ++j) {
      acc1[i][j] = (f32x4){0.f, 0.f, 0.f, 0.f};
      acc2[i][j] = (f32x4){0.f, 0.f, 0.f, 0.f};
    }

  for (int k0 = 0; k0 < 256; k0 += 32) {
    int koff = k0 + quad * 8;
    bf16x8 af[4], b1[4], b2[4];
#pragma unroll
    for (int mt = 0; mt < 4; ++mt) {
      int row = mbase + mt * 16 + r16;
      row = row < M ? row : M - 1;
      af[mt] = *(const bf16x8*)(A + (size_t)row * 256 + koff);
    }
#pragma unroll
    for (int nt = 0; nt < 4; ++nt) {
      int nrow = n0 + nt * 16 + r16;
      b1[nt] = *(const bf16x8*)(BT1 + (size_t)nrow * 256 + koff);
      b2[nt] = *(const bf16x8*)(BT2 + (size_t)nrow * 256 + koff);
    }
#pragma unroll
    for (int mt = 0; mt < 4; ++mt)
#pragma unroll
      for (int nt = 0; nt < 4; ++nt) {
        acc1[mt][nt] = __builtin_amdgcn_mfma_f32_16x16x32_bf16(af[mt], b1[nt], acc1[mt][nt], 0, 0, 0);
        acc2[mt][nt] = __builtin_amdgcn_mfma_f32_16x16x32_bf16(af[mt], b2[nt], acc2[mt][nt], 0, 0, 0);
      }
  }
#pragma unroll
  for (int mt = 0; mt < 4; ++mt) {
#pragma unroll
    for (int rr = 0; rr < 4; ++rr) {
      int grow = mbase + mt * 16 + quad * 4 + rr;
      if (grow < M) {
#pragma unroll
        for (int nt = 0; nt < 4; ++nt) {
          size_t o = (size_t)grow * 256 + n0 + nt * 16 + r16;
          C1[o] = f2bf(acc1[mt][nt][rr]);
          C2[o] = f2bf(acc2[mt][nt][rr]);
        }
      }
    }
  }
}

// ---- two-phase bucket sort for both CSRs (98 buckets, 512 nodes each) ------

// phase 0: bucket histogram for conv-dst and decoder-src (LDS-aggregated)
__global__ __launch_bounds__(256) void bucket_hist_kernel(const int* __restrict__ ei,
                                                          const int* __restrict__ ewi,
                                                          int* __restrict__ bcnt1,
                                                          int* __restrict__ bcnt2, int E) {
  __shared__ int c1[128], c2[128];
  int tid = threadIdx.x;
  if (tid < 128) { c1[tid] = 0; c2[tid] = 0; }
  __syncthreads();
  int idx = blockIdx.x * 256 + tid;
  int stride = gridDim.x * 256;
  for (int e = idx; e < E; e += stride) {
    atomicAdd(&c1[ei[E + e] >> WSHIFT], 1);
    atomicAdd(&c2[ewi[e] >> WSHIFT], 1);
  }
  __syncthreads();
  if (tid < 128) {
    if (c1[tid]) atomicAdd(&bcnt1[tid], c1[tid]);
    if (c2[tid]) atomicAdd(&bcnt2[tid], c2[tid]);
  }
}

// phase 0b: scan bucket counts -> bases + cursors; also rowp[N] = E
__global__ __launch_bounds__(128) void bucket_scan_kernel(const int* __restrict__ bcnt1,
                                                          const int* __restrict__ bcnt2,
                                                          int* __restrict__ bbase1,
                                                          int* __restrict__ bbase2,
                                                          int* __restrict__ gcur1,
                                                          int* __restrict__ gcur2,
                                                          int* __restrict__ rowp1,
                                                          int* __restrict__ rowp2, int N, int E) {
  __shared__ int ss[128];
  int tid = threadIdx.x;
  // CSR 1
  int v = (tid < NBUCK) ? bcnt1[tid] : 0;
  ss[tid] = v;
  __syncthreads();
  for (int off = 1; off < 128; off <<= 1) {
    int a = ss[tid];
    int b = (tid >= off) ? ss[tid - off] : 0;
    __syncthreads();
    ss[tid] = a + b;
    __syncthreads();
  }
  int excl = ss[tid] - v;
  if (tid < NBUCK) { bbase1[tid] = excl; gcur1[tid] = excl; }
  if (tid == NBUCK - 1) bbase1[NBUCK] = excl + v;
  __syncthreads();
  // CSR 2
  v = (tid < NBUCK) ? bcnt2[tid] : 0;
  ss[tid] = v;
  __syncthreads();
  for (int off = 1; off < 128; off <<= 1) {
    int a = ss[tid];
    int b = (tid >= off) ? ss[tid - off] : 0;
    __syncthreads();
    ss[tid] = a + b;
    __syncthreads();
  }
  excl = ss[tid] - v;
  if (tid < NBUCK) { bbase2[tid] = excl; gcur2[tid] = excl; }
  if (tid == NBUCK - 1) bbase2[NBUCK] = excl + v;
  if (tid == 0) { rowp1[N] = E; rowp2[N] = E; }
}

// phase 1 (conv): tile-ranked scatter into bucket staging, 4096 edges/block.
// stage.x = src | (dstLocal<<16), stage.y = attr bits
__global__ __launch_bounds__(256) void p1_conv_kernel(const int* __restrict__ ei,
                                                      const float* __restrict__ attr,
                                                      int* __restrict__ gcur,
                                                      int2* __restrict__ stage, int E) {
  __shared__ int cnt[128], cur[128];
  int tid = threadIdx.x;
  int base = blockIdx.x * 4096;
  if (tid < 128) cnt[tid] = 0;
  __syncthreads();
  int bk[16];
  int2 pl[16];
#pragma unroll
  for (int i = 0; i < 16; ++i) {
    int e = base + i * 256 + tid;
    bk[i] = -1;
    if (e < E) {
      int d = ei[E + e];
      int s = ei[e];
      bk[i] = d >> WSHIFT;
      pl[i] = make_int2(s | ((d & WMASK) << 16), __float_as_int(attr[e]));
      atomicAdd(&cnt[bk[i]], 1);
    }
  }
  __syncthreads();
  if (tid < NBUCK) {
    int c = cnt[tid];
    cur[tid] = c ? atomicAdd(&gcur[tid], c) : 0;
  }
  __syncthreads();
#pragma unroll
  for (int i = 0; i < 16; ++i) {
    if (bk[i] >= 0) {
      int pos = atomicAdd(&cur[bk[i]], 1);
      stage[pos] = pl[i];
    }
  }
}

// phase 1 (decoder): stage.x = dst | (srcLocal<<16), stage.y = edge_id
__global__ __launch_bounds__(256) void p1_dec_kernel(const int* __restrict__ ewi,
                                                     int* __restrict__ gcur,
                                                     int2* __restrict__ stage, int E) {
  __shared__ int cnt[128], cur[128];
  int tid = threadIdx.x;
  int base = blockIdx.x * 4096;
  if (tid < 128) cnt[tid] = 0;
  __syncthreads();
  int bk[16];
  int2 pl[16];
#pragma unroll
  for (int i = 0; i < 16; ++i) {
    int e = base + i * 256 + tid;
    bk[i] = -1;
    if (e < E) {
      int s = ewi[e];
      int d = ewi[E + e];
      bk[i] = s >> WSHIFT;
      pl[i] = make_int2(d | ((s & WMASK) << 16), e);
      atomicAdd(&cnt[bk[i]], 1);
    }
  }
  __syncthreads();
  if (tid < NBUCK) {
    int c = cnt[tid];
    cur[tid] = c ? atomicAdd(&gcur[tid], c) : 0;
  }
  __syncthreads();
#pragma unroll
  for (int i = 0; i < 16; ++i) {
    if (bk[i] >= 0) {
      int pos = atomicAdd(&cur[bk[i]], 1);
      stage[pos] = pl[i];
    }
  }
}

// phase 2 (both CSRs, gridDim.x = 2*NBUCK = 196): one block per bucket.
// LDS 512-bin node histogram (+deg for conv), scan, node-ordered CSR write.
__global__ __launch_bounds__(256) void p2_kernel(const int2* __restrict__ stage1,
                                                 const int* __restrict__ bbase1,
                                                 int2* __restrict__ esv,
                                                 int* __restrict__ rowp1,
                                                 float* __restrict__ dinv,
                                                 const int2* __restrict__ stage2,
                                                 const int* __restrict__ bbase2,
                                                 int2* __restrict__ eto,
                                                 int* __restrict__ rowp2, int N) {
  __shared__ int cnt[512];
  __shared__ float degs[512];
  __shared__ int pref[512];
  __shared__ int ss[256];
  int tid = threadIdx.x;
  bool isConv = blockIdx.x < NBUCK;
  int b = isConv ? blockIdx.x : blockIdx.x - NBUCK;
  const int2* stage = isConv ? stage1 : stage2;
  const int* bbase = isConv ? bbase1 : bbase2;
  int beg = bbase[b], end = bbase[b + 1];
  int node0 = b << WSHIFT;
  cnt[tid] = 0; cnt[tid + 256] = 0;
  degs[tid] = 0.f; degs[tid + 256] = 0.f;
  __syncthreads();
  for (int j = beg + tid; j < end; j += 256) {
    int2 p = stage[j];
    int loc = p.x >> 16;
    atomicAdd(&cnt[loc], 1);
    if (isConv) atomicAdd(&degs[loc], __int_as_float(p.y));
  }
  __syncthreads();
  // exclusive scan over 512 bins (each thread owns 2 consecutive)
  int c0 = cnt[2 * tid], c1 = cnt[2 * tid + 1];
  ss[tid] = c0 + c1;
  __syncthreads();
  for (int off = 1; off < 256; off <<= 1) {
    int a = ss[tid];
    int bb = (tid >= off) ? ss[tid - off] : 0;
    __syncthreads();
    ss[tid] = a + bb;
    __syncthreads();
  }
  int excl = (tid ? ss[tid - 1] : 0);
  pref[2 * tid] = excl;
  pref[2 * tid + 1] = excl + c0;
  __syncthreads();
#pragma unroll
  for (int h = 0; h < 2; ++h) {
    int i = tid + h * 256;
    int node = node0 + i;
    if (node < N) {
      if (isConv) {
        rowp1[node] = beg + pref[i];
        float d = degs[i];
        dinv[node] = d > 0.f ? 1.f / sqrtf(d) : 0.f;
      } else {
        rowp2[node] = beg + pref[i];
      }
    }
  }
  __syncthreads();
  int2* outb = isConv ? esv : eto;
  for (int j = beg + tid; j < end; j += 256) {
    int2 p = stage[j];
    int loc = p.x >> 16;
    int pos = beg + atomicAdd(&pref[loc], 1);
    outb[pos] = make_int2(p.x & 0xFFFF, p.y);
  }
}

// one wave per dst node, 8-lane decomposition: 8 lanes/edge x 8 edges/round.
// Lane g=lane&7 owns channels [g*32, g*32+32); slot q=lane>>3 handles edge jb+q.
__global__ __launch_bounds__(256) void gcn_gather(const unsigned short* __restrict__ xw,
                                                  const int* __restrict__ row_ptr,
                                                  const int2* __restrict__ esv,
                                                  const float* __restrict__ dinv,
                                                  unsigned short* __restrict__ ne, int N) {
  int node = blockIdx.x * 4 + (threadIdx.x >> 6);
  int lane = threadIdx.x & 63;
  int g = lane & 7, q = lane >> 3;
  if (node >= N) return;
  int beg = row_ptr[node], end = row_ptr[node + 1];
  float acc[32];
#pragma unroll
  for (int c = 0; c < 32; ++c) acc[c] = 0.f;
  const unsigned short* xb = xw + g * 32;
  if (beg < end) {
    int e0 = beg + q;
    int2 m0 = (e0 < end) ? esv[e0] : make_int2(0, 0);
    float v0 = (e0 < end) ? dinv[m0.x] * __int_as_float(m0.y) : 0.f;
    u16x8 r0[4];
#pragma unroll
    for (int h = 0; h < 4; ++h) r0[h] = *(const u16x8*)(xb + (size_t)m0.x * 256 + h * 8);
    for (int jb = beg; jb < end; jb += 8) {
      float v1 = 0.f;
      u16x8 r1[4];
#pragma unroll
      for (int h = 0; h < 4; ++h) r1[h] = r0[h];
      if (jb + 8 < end) {
        int e1 = jb + 8 + q;
        int2 m1 = (e1 < end) ? esv[e1] : make_int2(0, 0);
        v1 = (e1 < end) ? dinv[m1.x] * __int_as_float(m1.y) : 0.f;
#pragma unroll
        for (int h = 0; h < 4; ++h) r1[h] = *(const u16x8*)(xb + (size_t)m1.x * 256 + h * 8);
      }
#pragma unroll
      for (int h = 0; h < 4; ++h)
#pragma unroll
        for (int c = 0; c < 8; ++c) acc[h * 8 + c] += bf2f(r0[h][c]) * v0;
      v0 = v1;
#pragma unroll
      for (int h = 0; h < 4; ++h) r0[h] = r1[h];
    }
  }
  // cross-slot combine (8 partials over the same 32 channels)
#pragma unroll
  for (int c = 0; c < 32; ++c) {
    acc[c] += __shfl_xor(acc[c], 8, 64);
    acc[c] += __shfl_xor(acc[c], 16, 64);
    acc[c] += __shfl_xor(acc[c], 32, 64);
  }
  if (q == 0) {
    float dd = dinv[node];
#pragma unroll
    for (int h = 0; h < 4; ++h) {
      u16x8 o;
#pragma unroll
      for (int c = 0; c < 8; ++c) o[c] = f2bf(acc[h * 8 + c] * dd);
      *(u16x8*)(ne + (size_t)node * 256 + g * 32 + h * 8) = o;
    }
  }
}

// decode grouped by src, 8-lane decomposition: 8 lanes/edge x 8 edges/round.
// A[s]+b1 and w2 register-resident (32 ch/lane); 3-step reduce across g.
__global__ __launch_bounds__(256) void edge_decode_csr(const unsigned short* __restrict__ A,
                                                       const unsigned short* __restrict__ Bm,
                                                       const int* __restrict__ row_ptr,
                                                       const int2* __restrict__ eto,
                                                       const float* __restrict__ b1,
                                                       const float* __restrict__ w2,
                                                       const float* __restrict__ b2,
                                                       float* __restrict__ out, int N) {
  int node = blockIdx.x * 4 + (threadIdx.x >> 6);
  int lane = threadIdx.x & 63;
  int g = lane & 7, q = lane >> 3;
  if (node >= N) return;
  int beg = row_ptr[node], end = row_ptr[node + 1];
  if (beg >= end) return;
  float a[32], w[32];
  {
    const float4* bp = (const float4*)(b1 + g * 32);
    const float4* wp = (const float4*)(w2 + g * 32);
#pragma unroll
    for (int h = 0; h < 4; ++h) {
      u16x8 av = *(const u16x8*)(A + (size_t)node * 256 + g * 32 + h * 8);
      float4 b0 = bp[h * 2], b1v = bp[h * 2 + 1];
      float4 w0 = wp[h * 2], w1v = wp[h * 2 + 1];
      a[h * 8 + 0] = bf2f(av[0]) + b0.x;
      a[h * 8 + 1] = bf2f(av[1]) + b0.y;
      a[h * 8 + 2] = bf2f(av[2]) + b0.z;
      a[h * 8 + 3] = bf2f(av[3]) + b0.w;
      a[h * 8 + 4] = bf2f(av[4]) + b1v.x;
      a[h * 8 + 5] = bf2f(av[5]) + b1v.y;
      a[h * 8 + 6] = bf2f(av[6]) + b1v.z;
      a[h * 8 + 7] = bf2f(av[7]) + b1v.w;
      w[h * 8 + 0] = w0.x;
      w[h * 8 + 1] = w0.y;
      w[h * 8 + 2] = w0.z;
      w[h * 8 + 3] = w0.w;
      w[h * 8 + 4] = w1v.x;
      w[h * 8 + 5] = w1v.y;
      w[h * 8 + 6] = w1v.z;
      w[h * 8 + 7] = w1v.w;
    }
  }
  float base = b2[0];
  const unsigned short* Bb = Bm + g * 32;
  int e0 = beg + q;
  int2 m0 = (e0 < end) ? eto[e0] : make_int2(0, -1);
  u16x8 r0[4];
#pragma unroll
  for (int h = 0; h < 4; ++h) r0[h] = *(const u16x8*)(Bb + (size_t)m0.x * 256 + h * 8);
  for (int jb = beg; jb < end; jb += 8) {
    int2 m1 = make_int2(0, -1);
    u16x8 r1[4];
#pragma unroll
    for (int h = 0; h < 4; ++h) r1[h] = r0[h];
    if (jb + 8 < end) {
      int e1 = jb + 8 + q;
      m1 = (e1 < end) ? eto[e1] : make_int2(0, -1);
#pragma unroll
      for (int h = 0; h < 4; ++h) r1[h] = *(const u16x8*)(Bb + (size_t)m1.x * 256 + h * 8);
    }
    float s = 0.f;
#pragma unroll
    for (int h = 0; h < 4; ++h)
#pragma unroll
      for (int c = 0; c < 8; ++c)
        s += fmaxf(a[h * 8 + c] + bf2f(r0[h][c]), 0.f) * w[h * 8 + c];
    s += __shfl_xor(s, 1, 64);
    s += __shfl_xor(s, 2, 64);
    s += __shfl_xor(s, 4, 64);
    if (g == 0 && m0.y >= 0) out[m0.y] = s + base;
    m0 = m1;
#pragma unroll
    for (int h = 0; h < 4; ++h) r0[h] = r1[h];
  }
}

extern "C" void kernel_launch(void* const* d_in, const int* in_sizes, int n_in,
                              void* d_out, int out_size, void* d_ws, size_t ws_size,
                              hipStream_t stream) {
  const float* x      = (const float*)d_in[0];
  const int*   ei     = (const int*)d_in[1];
  const float* attr   = (const float*)d_in[2];
  const int*   ewi    = (const int*)d_in[3];
  const float* p_pool = (const float*)d_in[4];
  const float* W_ih   = (const float*)d_in[5];
  const float* W_hh   = (const float*)d_in[6];
  const float* b_ih   = (const float*)d_in[7];
  const float* b_hh   = (const float*)d_in[8];
  const float* W_init = (const float*)d_in[9];
  const float* lin1_w = (const float*)d_in[10];
  const float* lin1_b = (const float*)d_in[11];
  const float* lin2_w = (const float*)d_in[12];
  const float* lin2_b = (const float*)d_in[13];
  float* out = (float*)d_out;

  const int C = 256;
  const int N = in_sizes[0] / C;   // 50000
  const int E = in_sizes[2];       // 800000

  // ---- workspace layout (256B aligned) ----
  char* ws = (char*)d_ws;
  size_t off = 0;
  auto alloc = [&](size_t bytes) {
    size_t o = off;
    off = (off + bytes + 255) & ~(size_t)255;
    return o;
  };
  float*          score  = (float*)(ws + alloc((size_t)N * 4));
  int*            perm   = (int*)(ws + alloc(C * 4));
  float*          tts    = (float*)(ws + alloc(C * 4));
  unsigned short* WevoT  = (unsigned short*)(ws + alloc((size_t)C * C * 2));
  unsigned short* WA     = (unsigned short*)(ws + alloc((size_t)C * C * 2));
  unsigned short* WB     = (unsigned short*)(ws + alloc((size_t)C * C * 2));
  // contiguous zero region: ghist | bcnt1 | bcnt2
  int   zeroInts = 4096 + 128 + 128;
  char* zbase    = ws + alloc((size_t)zeroInts * 4);
  int* ghist = (int*)zbase;
  int* bcnt1 = (int*)(zbase + 4096 * 4);
  int* bcnt2 = (int*)(zbase + 4096 * 4 + 128 * 4);
  int*            bbase1 = (int*)(ws + alloc((NBUCK + 1) * 4));
  int*            bbase2 = (int*)(ws + alloc((NBUCK + 1) * 4));
  int*            gcur1  = (int*)(ws + alloc(128 * 4));
  int*            gcur2  = (int*)(ws + alloc(128 * 4));
  float*          dinv   = (float*)(ws + alloc((size_t)N * 4));
  int*            rowp1  = (int*)(ws + alloc((size_t)(N + 1) * 4));
  int*            rowp2  = (int*)(ws + alloc((size_t)(N + 1) * 4));
  int2*           stage1 = (int2*)(ws + alloc((size_t)E * 8));
  int2*           stage2 = (int2*)(ws + alloc((size_t)E * 8));
  int2*           esv    = (int2*)(ws + alloc((size_t)E * 8));
  int2*           eto    = (int2*)(ws + alloc((size_t)E * 8));
  unsigned short* xh     = (unsigned short*)(ws + alloc((size_t)N * C * 2));
  unsigned short* xwh    = (unsigned short*)(ws + alloc((size_t)N * C * 2));
  unsigned short* Bbf    = (unsigned short*)(ws + alloc((size_t)N * C * 2));
  // aliases (stream-ordered producers/consumers):
  unsigned short* ne  = xh;   // xh dead after GEMM1
  unsigned short* Abf = xwh;  // xwh dead after gather

  // 0) zero ghist/bcnt in one tiny launch
  zero_kernel<<<(zeroInts / 4 + 255) / 256, 256, 0, stream>>>((float4*)zbase, zeroInts / 4);

  // 1) score (+||p||) + bf16 cast of x
  score_cast_kernel<<<(N + 3) / 4, 256, 0, stream>>>(x, p_pool, score, xh, N);

  // 2) exact top-256: LDS-aggregated histogram -> fused select+collect+sort
  hist12_kernel<<<64, 256, 0, stream>>>(score, N, ghist);
  topk_kernel<<<1, 1024, 0, stream>>>(score, N, C, ghist, perm, tts);

  // 3+4) GRU (x_tilde inline) -> evolved W (transposed bf16)
  gru_kernel<<<C, C, 0, stream>>>(x, perm, tts, W_init, W_ih, W_hh, b_ih, b_hh, WevoT);

  // 5) xw = x @ Wevo (bf16 MFMA, bf16 out)
  mfma_gemm_bf16<<<(N + 63) / 64, 256, 0, stream>>>(xh, WevoT, xwh, N);

  // 6) two-phase bucket sort for both CSRs (also produces deg/dinv in p2)
  bucket_hist_kernel<<<256, 256, 0, stream>>>(ei, ewi, bcnt1, bcnt2, E);
  bucket_scan_kernel<<<1, 128, 0, stream>>>(bcnt1, bcnt2, bbase1, bbase2, gcur1, gcur2,
                                            rowp1, rowp2, N, E);
  p1_conv_kernel<<<(E + 4095) / 4096, 256, 0, stream>>>(ei, attr, gcur1, stage1, E);
  p1_dec_kernel<<<(E + 4095) / 4096, 256, 0, stream>>>(ewi, gcur2, stage2, E);
  p2_kernel<<<2 * NBUCK, 256, 0, stream>>>(stage1, bbase1, esv, rowp1, dinv,
                                           stage2, bbase2, eto, rowp2, N);

  // 7) gather (8-lane decomposition)
  gcn_gather<<<(N + 3) / 4, 256, 0, stream>>>(xwh, rowp1, esv, dinv, ne, N);

  // 8) decoder projections fused (lin1_w rows ARE the B^T layout)
  lin1_cast_kernel<<<(2 * C * C) / 256, 256, 0, stream>>>(lin1_w, WA, WB);
  mfma_gemm_bf16_dual<<<(N + 63) / 64, 256, 0, stream>>>(ne, WA, WB, Abf, Bbf, N);

  // 9) edge decode (8-lane decomposition)
  edge_decode_csr<<<(N + 3) / 4, 256, 0, stream>>>(Abf, Bbf, rowp2, eto,
                                                   lin1_b, lin2_w, lin2_b, out, N);
}

// Round 11
// 505.125 us; speedup vs baseline: 1.4516x; 1.1718x over previous
//
#include <hip/hip_runtime.h>
#include <hip/hip_bf16.h>
#include <math.h>

// ---------------------------------------------------------------------------
// EvolveGCNH + GCNConv + EdgeDecoder.
// R1: atomic scatter -> dst-CSR register gather (3574 -> 1223 us).
// R3/R4: bf16 MFMA GEMMs, bf16 operands, src-CSR grouped decode.
// R5: parallel top-k, merged CSR builds, dual GEMM (962 us).
// R7: two-phase bucket sort for both CSRs (609 us).
// R8: QUAD decomposition gather/decode + kernel fusion (522 us; decode 71 us
//     at VGPR 36 / occ 60%).
// R9: REGRESSED (733): global-atomic score hist (hot bins) + 391-bucket
//     sort (42 B runs < line).
// R10: sort/hist reverted (592) but kept 8-lane gather/decode -> decode 149 us:
//     VGPR 60, occ 37%, VALUBusy 28% — per-wave state killed occupancy-based
//     latency hiding. Lesson: 16 ch/lane (quad) is the sweet spot.
// R11: revert gather/decode to R8's measured quad kernels; keep R10's
//      merged 196-block p2, separate LDS hist12, fused score_cast.
// ---------------------------------------------------------------------------

typedef __attribute__((ext_vector_type(8))) short bf16x8;
typedef __attribute__((ext_vector_type(8))) unsigned short u16x8;
typedef __attribute__((ext_vector_type(4))) float f32x4;

#define WSHIFT 9              // 512 nodes per bucket
#define WMASK 511
#define NBUCK 98              // ceil(50000/512)

__device__ __forceinline__ unsigned f2key(float f) {
  unsigned u = __float_as_uint(f);
  return (u & 0x80000000u) ? ~u : (u | 0x80000000u);
}

// round-to-nearest-even fp32 -> bf16 bits
__device__ __forceinline__ unsigned short f2bf(float f) {
  unsigned u = __float_as_uint(f);
  unsigned r = u + 0x7fffu + ((u >> 16) & 1u);
  return (unsigned short)(r >> 16);
}
__device__ __forceinline__ float bf2f(unsigned short h) {
  return __uint_as_float((unsigned)h << 16);
}

__global__ void zero_kernel(float4* __restrict__ p, int n4) {
  int i = blockIdx.x * blockDim.x + threadIdx.x;
  if (i < n4) p[i] = make_float4(0.f, 0.f, 0.f, 0.f);
}

// score (incl. ||p||) + bf16 cast of x in one pass (x read once)
__global__ __launch_bounds__(256) void score_cast_kernel(const float* __restrict__ x,
                                                         const float* __restrict__ p,
                                                         float* __restrict__ score,
                                                         unsigned short* __restrict__ xh, int N) {
  int node = blockIdx.x * 4 + (threadIdx.x >> 6);
  int lane = threadIdx.x & 63;
  if (node >= N) return;
  float4 xv = ((const float4*)(x + (size_t)node * 256))[lane];
  ushort4 hv;
  hv.x = f2bf(xv.x);
  hv.y = f2bf(xv.y);
  hv.z = f2bf(xv.z);
  hv.w = f2bf(xv.w);
  ((ushort4*)(xh + (size_t)node * 256))[lane] = hv;
  float4 pv = ((const float4*)p)[lane];
  float s = xv.x * pv.x + xv.y * pv.y + xv.z * pv.z + xv.w * pv.w;
  float sp = pv.x * pv.x + pv.y * pv.y + pv.z * pv.z + pv.w * pv.w;
#pragma unroll
  for (int off = 32; off > 0; off >>= 1) {
    s += __shfl_down(s, off, 64);
    sp += __shfl_down(sp, off, 64);
  }
  if (lane == 0) score[node] = s / sqrtf(sp);
}

// grid-wide histogram of the top 12 key bits (4096 bins), LDS-aggregated
__global__ __launch_bounds__(256) void hist12_kernel(const float* __restrict__ score, int n,
                                                     int* __restrict__ gh) {
  __shared__ int lh[4096];
  int tid = threadIdx.x;
  for (int i = tid; i < 4096; i += 256) lh[i] = 0;
  __syncthreads();
  int idx = blockIdx.x * 256 + tid;
  int stride = gridDim.x * 256;
  for (int i = idx; i < n; i += stride) {
    unsigned key = f2key(score[i]);
    atomicAdd(&lh[key >> 20], 1);
  }
  __syncthreads();
  for (int i = tid; i < 4096; i += 256) {
    int v = lh[i];
    if (v) atomicAdd(&gh[i], v);
  }
}

// select (suffix-scan over 4096-bin histogram -> bin-floor threshold) fused
// with collect + bitonic sort (key desc, idx asc) -> perm[k], tanh(score).
__global__ __launch_bounds__(1024) void topk_kernel(const float* __restrict__ score, int n, int k,
                                                    const int* __restrict__ gh,
                                                    int* __restrict__ perm,
                                                    float* __restrict__ tts) {
  __shared__ int part[1024];
  __shared__ unsigned sT;
  int tid = threadIdx.x;
  {
    int b0 = tid * 4;
    int s0 = gh[b0], s1 = gh[b0 + 1], s2 = gh[b0 + 2], s3 = gh[b0 + 3];
    part[tid] = s0 + s1 + s2 + s3;
    __syncthreads();
    for (int off = 1; off < 1024; off <<= 1) {
      int v = part[tid];
      int add = (tid + off < 1024) ? part[tid + off] : 0;
      __syncthreads();
      part[tid] = v + add;
      __syncthreads();
    }
    int sufChunk = part[tid];
    int sufNext = (tid < 1023) ? part[tid + 1] : 0;
    if (sufNext < k && sufChunk >= k) {
      int run = sufNext;
      int b;
      run += s3;
      if (run >= k) b = b0 + 3;
      else {
        run += s2;
        if (run >= k) b = b0 + 2;
        else {
          run += s1;
          b = (run >= k) ? b0 + 1 : b0;
        }
      }
      sT = ((unsigned)b) << 20;
    }
  }
  __syncthreads();
  unsigned T = sT;
  __shared__ unsigned keys[1024];
  __shared__ int idxs[1024];
  __shared__ int cnt;
  if (tid == 0) cnt = 0;
  keys[tid] = 0u;
  idxs[tid] = 0x7fffffff;
  __syncthreads();
  for (int i = tid; i < n; i += 1024) {
    unsigned key = f2key(score[i]);
    if (key >= T) {
      int p = atomicAdd(&cnt, 1);
      if (p < 1024) { keys[p] = key; idxs[p] = i; }
    }
  }
  __syncthreads();
  for (int size = 2; size <= 1024; size <<= 1) {
    for (int stride = size >> 1; stride > 0; stride >>= 1) {
      int j = tid ^ stride;
      if (j > tid) {
        unsigned ka = keys[tid], kb = keys[j];
        int ia = idxs[tid], ib = idxs[j];
        bool aBefore = (ka > kb) || (ka == kb && ia < ib);
        bool up = ((tid & size) == 0);
        if (aBefore != up) {
          keys[tid] = kb; keys[j] = ka;
          idxs[tid] = ib; idxs[j] = ia;
        }
      }
      __syncthreads();
    }
  }
  if (tid < k) {
    int idx = idxs[tid];
    perm[tid] = idx;
    tts[tid] = tanhf(score[idx]);
  }
}

// GRU step with x_tilde computed inline (row i = x[perm[i]] * tts[i]);
// writes evolved W TRANSPOSED as bf16: WevoT[n*256 + k] = bf16(W[k][n])
__global__ __launch_bounds__(256) void gru_kernel(const float* __restrict__ x,
                                                  const int* __restrict__ perm,
                                                  const float* __restrict__ tts,
                                                  const float* __restrict__ Wi,
                                                  const float* __restrict__ W_ih,
                                                  const float* __restrict__ W_hh,
                                                  const float* __restrict__ b_ih,
                                                  const float* __restrict__ b_hh,
                                                  unsigned short* __restrict__ WevoT) {
  int i = blockIdx.x, j = threadIdx.x;  // i = k-row of W, j = n-col
  __shared__ float sx[256], sh[256];
  sx[j] = x[(size_t)perm[i] * 256 + j] * tts[i];
  sh[j] = Wi[i * 256 + j];
  __syncthreads();
  float gi[3], gh[3];
#pragma unroll
  for (int g = 0; g < 3; ++g) {
    int row = g * 256 + j;
    const float4* wi4 = (const float4*)(W_ih + (size_t)row * 256);
    const float4* wh4 = (const float4*)(W_hh + (size_t)row * 256);
    float si = 0.f, s2 = 0.f;
    for (int k4 = 0; k4 < 64; ++k4) {
      float4 wv = wi4[k4];
      float4 hv = wh4[k4];
      int k = k4 * 4;
      si += sx[k] * wv.x + sx[k + 1] * wv.y + sx[k + 2] * wv.z + sx[k + 3] * wv.w;
      s2 += sh[k] * hv.x + sh[k + 1] * hv.y + sh[k + 2] * hv.z + sh[k + 3] * hv.w;
    }
    gi[g] = si + b_ih[row];
    gh[g] = s2 + b_hh[row];
  }
  float r = 1.f / (1.f + expf(-(gi[0] + gh[0])));
  float z = 1.f / (1.f + expf(-(gi[1] + gh[1])));
  float nn = tanhf(gi[2] + r * gh[2]);
  float w = (1.f - z) * nn + z * sh[j];
  WevoT[(size_t)j * 256 + i] = f2bf(w);
}

// lin1_w [256][512] -> WA/WB bf16 each [256][256] at [n][k] (= B^T layout)
__global__ __launch_bounds__(256) void lin1_cast_kernel(const float* __restrict__ lin1,
                                                        unsigned short* __restrict__ WA,
                                                        unsigned short* __restrict__ WB) {
  int idx = blockIdx.x * 256 + threadIdx.x;  // 131072 total
  int n = idx >> 9, k = idx & 511;
  unsigned short h = f2bf(lin1[idx]);
  if (k < 256)
    WA[n * 256 + k] = h;
  else
    WB[n * 256 + (k - 256)] = h;
}

// ---------------------------------------------------------------------------
// Pure-bf16 MFMA GEMM: C[M,256] = A[M,256] @ B[256,256], bf16 in/out, fp32 acc.
// A row-major bf16; B as B^T rows (BT[n][k]). Layouts HW-verified (R3/R4).
// ---------------------------------------------------------------------------
__global__ __launch_bounds__(256) void mfma_gemm_bf16(const unsigned short* __restrict__ A,
                                                      const unsigned short* __restrict__ BT,
                                                      unsigned short* __restrict__ Cout, int M) {
  int tid = threadIdx.x;
  int wave = tid >> 6, lane = tid & 63;
  int quad = lane >> 4, r16 = lane & 15;
  int n0 = wave * 64;
  int mbase = blockIdx.x * 64;

  f32x4 acc[4][4];
#pragma unroll
  for (int i = 0; i < 4; ++i)
#pragma unroll
    for (int j = 0; j < 4; ++j) acc[i][j] = (f32x4){0.f, 0.f, 0.f, 0.f};

  for (int k0 = 0; k0 < 256; k0 += 32) {
    int koff = k0 + quad * 8;
    bf16x8 af[4], bf[4];
#pragma unroll
    for (int mt = 0; mt < 4; ++mt) {
      int row = mbase + mt * 16 + r16;
      row = row < M ? row : M - 1;
      af[mt] = *(const bf16x8*)(A + (size_t)row * 256 + koff);
    }
#pragma unroll
    for (int nt = 0; nt < 4; ++nt) {
      int nrow = n0 + nt * 16 + r16;
      bf[nt] = *(const bf16x8*)(BT + (size_t)nrow * 256 + koff);
    }
#pragma unroll
    for (int mt = 0; mt < 4; ++mt)
#pragma unroll
      for (int nt = 0; nt < 4; ++nt)
        acc[mt][nt] = __builtin_amdgcn_mfma_f32_16x16x32_bf16(af[mt], bf[nt], acc[mt][nt], 0, 0, 0);
  }
#pragma unroll
  for (int mt = 0; mt < 4; ++mt) {
#pragma unroll
    for (int rr = 0; rr < 4; ++rr) {
      int grow = mbase + mt * 16 + quad * 4 + rr;
      if (grow < M) {
#pragma unroll
        for (int nt = 0; nt < 4; ++nt)
          Cout[(size_t)grow * 256 + n0 + nt * 16 + r16] = f2bf(acc[mt][nt][rr]);
      }
    }
  }
}

// Dual variant: reads A once, produces C1 = A@B1 and C2 = A@B2.
__global__ __launch_bounds__(256) void mfma_gemm_bf16_dual(const unsigned short* __restrict__ A,
                                                           const unsigned short* __restrict__ BT1,
                                                           const unsigned short* __restrict__ BT2,
                                                           unsigned short* __restrict__ C1,
                                                           unsigned short* __restrict__ C2, int M) {
  int tid = threadIdx.x;
  int wave = tid >> 6, lane = tid & 63;
  int quad = lane >> 4, r16 = lane & 15;
  int n0 = wave * 64;
  int mbase = blockIdx.x * 64;

  f32x4 acc1[4][4], acc2[4][4];
#pragma unroll
  for (int i = 0; i < 4; ++i)
#pragma unroll
    for (int j = 0; j < 4; ++j) {
      acc1[i][j] = (f32x4){0.f, 0.f, 0.f, 0.f};
      acc2[i][j] = (f32x4){0.f, 0.f, 0.f, 0.f};
    }

  for (int k0 = 0; k0 < 256; k0 += 32) {
    int koff = k0 + quad * 8;
    bf16x8 af[4], b1[4], b2[4];
#pragma unroll
    for (int mt = 0; mt < 4; ++mt) {
      int row = mbase + mt * 16 + r16;
      row = row < M ? row : M - 1;
      af[mt] = *(const bf16x8*)(A + (size_t)row * 256 + koff);
    }
#pragma unroll
    for (int nt = 0; nt < 4; ++nt) {
      int nrow = n0 + nt * 16 + r16;
      b1[nt] = *(const bf16x8*)(BT1 + (size_t)nrow * 256 + koff);
      b2[nt] = *(const bf16x8*)(BT2 + (size_t)nrow * 256 + koff);
    }
#pragma unroll
    for (int mt = 0; mt < 4; ++mt)
#pragma unroll
      for (int nt = 0; nt < 4; ++nt) {
        acc1[mt][nt] = __builtin_amdgcn_mfma_f32_16x16x32_bf16(af[mt], b1[nt], acc1[mt][nt], 0, 0, 0);
        acc2[mt][nt] = __builtin_amdgcn_mfma_f32_16x16x32_bf16(af[mt], b2[nt], acc2[mt][nt], 0, 0, 0);
      }
  }
#pragma unroll
  for (int mt = 0; mt < 4; ++mt) {
#pragma unroll
    for (int rr = 0; rr < 4; ++rr) {
      int grow = mbase + mt * 16 + quad * 4 + rr;
      if (grow < M) {
#pragma unroll
        for (int nt = 0; nt < 4; ++nt) {
          size_t o = (size_t)grow * 256 + n0 + nt * 16 + r16;
          C1[o] = f2bf(acc1[mt][nt][rr]);
          C2[o] = f2bf(acc2[mt][nt][rr]);
        }
      }
    }
  }
}

// ---- two-phase bucket sort for both CSRs (98 buckets, 512 nodes each) ------

// phase 0: bucket histogram for conv-dst and decoder-src (LDS-aggregated)
__global__ __launch_bounds__(256) void bucket_hist_kernel(const int* __restrict__ ei,
                                                          const int* __restrict__ ewi,
                                                          int* __restrict__ bcnt1,
                                                          int* __restrict__ bcnt2, int E) {
  __shared__ int c1[128], c2[128];
  int tid = threadIdx.x;
  if (tid < 128) { c1[tid] = 0; c2[tid] = 0; }
  __syncthreads();
  int idx = blockIdx.x * 256 + tid;
  int stride = gridDim.x * 256;
  for (int e = idx; e < E; e += stride) {
    atomicAdd(&c1[ei[E + e] >> WSHIFT], 1);
    atomicAdd(&c2[ewi[e] >> WSHIFT], 1);
  }
  __syncthreads();
  if (tid < 128) {
    if (c1[tid]) atomicAdd(&bcnt1[tid], c1[tid]);
    if (c2[tid]) atomicAdd(&bcnt2[tid], c2[tid]);
  }
}

// phase 0b: scan bucket counts -> bases + cursors; also rowp[N] = E
__global__ __launch_bounds__(128) void bucket_scan_kernel(const int* __restrict__ bcnt1,
                                                          const int* __restrict__ bcnt2,
                                                          int* __restrict__ bbase1,
                                                          int* __restrict__ bbase2,
                                                          int* __restrict__ gcur1,
                                                          int* __restrict__ gcur2,
                                                          int* __restrict__ rowp1,
                                                          int* __restrict__ rowp2, int N, int E) {
  __shared__ int ss[128];
  int tid = threadIdx.x;
  // CSR 1
  int v = (tid < NBUCK) ? bcnt1[tid] : 0;
  ss[tid] = v;
  __syncthreads();
  for (int off = 1; off < 128; off <<= 1) {
    int a = ss[tid];
    int b = (tid >= off) ? ss[tid - off] : 0;
    __syncthreads();
    ss[tid] = a + b;
    __syncthreads();
  }
  int excl = ss[tid] - v;
  if (tid < NBUCK) { bbase1[tid] = excl; gcur1[tid] = excl; }
  if (tid == NBUCK - 1) bbase1[NBUCK] = excl + v;
  __syncthreads();
  // CSR 2
  v = (tid < NBUCK) ? bcnt2[tid] : 0;
  ss[tid] = v;
  __syncthreads();
  for (int off = 1; off < 128; off <<= 1) {
    int a = ss[tid];
    int b = (tid >= off) ? ss[tid - off] : 0;
    __syncthreads();
    ss[tid] = a + b;
    __syncthreads();
  }
  excl = ss[tid] - v;
  if (tid < NBUCK) { bbase2[tid] = excl; gcur2[tid] = excl; }
  if (tid == NBUCK - 1) bbase2[NBUCK] = excl + v;
  if (tid == 0) { rowp1[N] = E; rowp2[N] = E; }
}

// phase 1 (conv): tile-ranked scatter into bucket staging, 4096 edges/block.
// stage.x = src | (dstLocal<<16), stage.y = attr bits
__global__ __launch_bounds__(256) void p1_conv_kernel(const int* __restrict__ ei,
                                                      const float* __restrict__ attr,
                                                      int* __restrict__ gcur,
                                                      int2* __restrict__ stage, int E) {
  __shared__ int cnt[128], cur[128];
  int tid = threadIdx.x;
  int base = blockIdx.x * 4096;
  if (tid < 128) cnt[tid] = 0;
  __syncthreads();
  int bk[16];
  int2 pl[16];
#pragma unroll
  for (int i = 0; i < 16; ++i) {
    int e = base + i * 256 + tid;
    bk[i] = -1;
    if (e < E) {
      int d = ei[E + e];
      int s = ei[e];
      bk[i] = d >> WSHIFT;
      pl[i] = make_int2(s | ((d & WMASK) << 16), __float_as_int(attr[e]));
      atomicAdd(&cnt[bk[i]], 1);
    }
  }
  __syncthreads();
  if (tid < NBUCK) {
    int c = cnt[tid];
    cur[tid] = c ? atomicAdd(&gcur[tid], c) : 0;
  }
  __syncthreads();
#pragma unroll
  for (int i = 0; i < 16; ++i) {
    if (bk[i] >= 0) {
      int pos = atomicAdd(&cur[bk[i]], 1);
      stage[pos] = pl[i];
    }
  }
}

// phase 1 (decoder): stage.x = dst | (srcLocal<<16), stage.y = edge_id
__global__ __launch_bounds__(256) void p1_dec_kernel(const int* __restrict__ ewi,
                                                     int* __restrict__ gcur,
                                                     int2* __restrict__ stage, int E) {
  __shared__ int cnt[128], cur[128];
  int tid = threadIdx.x;
  int base = blockIdx.x * 4096;
  if (tid < 128) cnt[tid] = 0;
  __syncthreads();
  int bk[16];
  int2 pl[16];
#pragma unroll
  for (int i = 0; i < 16; ++i) {
    int e = base + i * 256 + tid;
    bk[i] = -1;
    if (e < E) {
      int s = ewi[e];
      int d = ewi[E + e];
      bk[i] = s >> WSHIFT;
      pl[i] = make_int2(d | ((s & WMASK) << 16), e);
      atomicAdd(&cnt[bk[i]], 1);
    }
  }
  __syncthreads();
  if (tid < NBUCK) {
    int c = cnt[tid];
    cur[tid] = c ? atomicAdd(&gcur[tid], c) : 0;
  }
  __syncthreads();
#pragma unroll
  for (int i = 0; i < 16; ++i) {
    if (bk[i] >= 0) {
      int pos = atomicAdd(&cur[bk[i]], 1);
      stage[pos] = pl[i];
    }
  }
}

// phase 2 (both CSRs, gridDim.x = 2*NBUCK = 196): one block per bucket.
// LDS 512-bin node histogram (+deg for conv), scan, node-ordered CSR write.
__global__ __launch_bounds__(256) void p2_kernel(const int2* __restrict__ stage1,
                                                 const int* __restrict__ bbase1,
                                                 int2* __restrict__ esv,
                                                 int* __restrict__ rowp1,
                                                 float* __restrict__ dinv,
                                                 const int2* __restrict__ stage2,
                                                 const int* __restrict__ bbase2,
                                                 int2* __restrict__ eto,
                                                 int* __restrict__ rowp2, int N) {
  __shared__ int cnt[512];
  __shared__ float degs[512];
  __shared__ int pref[512];
  __shared__ int ss[256];
  int tid = threadIdx.x;
  bool isConv = blockIdx.x < NBUCK;
  int b = isConv ? blockIdx.x : blockIdx.x - NBUCK;
  const int2* stage = isConv ? stage1 : stage2;
  const int* bbase = isConv ? bbase1 : bbase2;
  int beg = bbase[b], end = bbase[b + 1];
  int node0 = b << WSHIFT;
  cnt[tid] = 0; cnt[tid + 256] = 0;
  degs[tid] = 0.f; degs[tid + 256] = 0.f;
  __syncthreads();
  for (int j = beg + tid; j < end; j += 256) {
    int2 p = stage[j];
    int loc = p.x >> 16;
    atomicAdd(&cnt[loc], 1);
    if (isConv) atomicAdd(&degs[loc], __int_as_float(p.y));
  }
  __syncthreads();
  // exclusive scan over 512 bins (each thread owns 2 consecutive)
  int c0 = cnt[2 * tid], c1 = cnt[2 * tid + 1];
  ss[tid] = c0 + c1;
  __syncthreads();
  for (int off = 1; off < 256; off <<= 1) {
    int a = ss[tid];
    int bb = (tid >= off) ? ss[tid - off] : 0;
    __syncthreads();
    ss[tid] = a + bb;
    __syncthreads();
  }
  int excl = (tid ? ss[tid - 1] : 0);
  pref[2 * tid] = excl;
  pref[2 * tid + 1] = excl + c0;
  __syncthreads();
#pragma unroll
  for (int h = 0; h < 2; ++h) {
    int i = tid + h * 256;
    int node = node0 + i;
    if (node < N) {
      if (isConv) {
        rowp1[node] = beg + pref[i];
        float d = degs[i];
        dinv[node] = d > 0.f ? 1.f / sqrtf(d) : 0.f;
      } else {
        rowp2[node] = beg + pref[i];
      }
    }
  }
  __syncthreads();
  int2* outb = isConv ? esv : eto;
  for (int j = beg + tid; j < end; j += 256) {
    int2 p = stage[j];
    int loc = p.x >> 16;
    int pos = beg + atomicAdd(&pref[loc], 1);
    outb[pos] = make_int2(p.x & 0xFFFF, p.y);
  }
}

// one wave per dst node, quad decomposition: 16 lanes/edge x 4 edges/iteration.
// Lane g=lane&15 owns channels [g*16, g*16+16); quad q processes edge jb+q.
__global__ __launch_bounds__(256) void gcn_gather(const unsigned short* __restrict__ xw,
                                                  const int* __restrict__ row_ptr,
                                                  const int2* __restrict__ esv,
                                                  const float* __restrict__ dinv,
                                                  unsigned short* __restrict__ ne, int N) {
  int node = blockIdx.x * 4 + (threadIdx.x >> 6);
  int lane = threadIdx.x & 63;
  int g = lane & 15, q = lane >> 4;
  if (node >= N) return;
  int beg = row_ptr[node], end = row_ptr[node + 1];
  float acc[16];
#pragma unroll
  for (int c = 0; c < 16; ++c) acc[c] = 0.f;
  const unsigned short* xb = xw + g * 16;
  if (beg < end) {
    int e0 = beg + q;
    int2 m0 = (e0 < end) ? esv[e0] : make_int2(0, 0);
    float v0 = (e0 < end) ? dinv[m0.x] * __int_as_float(m0.y) : 0.f;
    u16x8 r0a = *(const u16x8*)(xb + (size_t)m0.x * 256);
    u16x8 r0b = *(const u16x8*)(xb + (size_t)m0.x * 256 + 8);
    for (int jb = beg; jb < end; jb += 4) {
      float v1 = 0.f;
      u16x8 r1a = r0a, r1b = r0b;
      if (jb + 4 < end) {
        int e1 = jb + 4 + q;
        int2 m1 = (e1 < end) ? esv[e1] : make_int2(0, 0);
        v1 = (e1 < end) ? dinv[m1.x] * __int_as_float(m1.y) : 0.f;
        r1a = *(const u16x8*)(xb + (size_t)m1.x * 256);
        r1b = *(const u16x8*)(xb + (size_t)m1.x * 256 + 8);
      }
#pragma unroll
      for (int c = 0; c < 8; ++c) acc[c] += bf2f(r0a[c]) * v0;
#pragma unroll
      for (int c = 0; c < 8; ++c) acc[8 + c] += bf2f(r0b[c]) * v0;
      v0 = v1; r0a = r1a; r0b = r1b;
    }
  }
  // cross-quad combine (each quad holds a partial over the same channels)
#pragma unroll
  for (int c = 0; c < 16; ++c) {
    acc[c] += __shfl_xor(acc[c], 16, 64);
    acc[c] += __shfl_xor(acc[c], 32, 64);
  }
  if (q == 0) {
    float dd = dinv[node];
    u16x8 o0, o1;
#pragma unroll
    for (int c = 0; c < 8; ++c) {
      o0[c] = f2bf(acc[c] * dd);
      o1[c] = f2bf(acc[8 + c] * dd);
    }
    *(u16x8*)(ne + (size_t)node * 256 + g * 16) = o0;
    *(u16x8*)(ne + (size_t)node * 256 + g * 16 + 8) = o1;
  }
}

// decode grouped by src, quad decomposition: 16 lanes/edge x 4 edges/iteration.
// A[s]+b1 and w2 register-resident per lane (16 channels); 4-step quad reduce.
__global__ __launch_bounds__(256) void edge_decode_csr(const unsigned short* __restrict__ A,
                                                       const unsigned short* __restrict__ Bm,
                                                       const int* __restrict__ row_ptr,
                                                       const int2* __restrict__ eto,
                                                       const float* __restrict__ b1,
                                                       const float* __restrict__ w2,
                                                       const float* __restrict__ b2,
                                                       float* __restrict__ out, int N) {
  int node = blockIdx.x * 4 + (threadIdx.x >> 6);
  int lane = threadIdx.x & 63;
  int g = lane & 15, q = lane >> 4;
  if (node >= N) return;
  int beg = row_ptr[node], end = row_ptr[node + 1];
  if (beg >= end) return;
  float a[16], w[16];
  {
    u16x8 a0 = *(const u16x8*)(A + (size_t)node * 256 + g * 16);
    u16x8 a1 = *(const u16x8*)(A + (size_t)node * 256 + g * 16 + 8);
    const float4* bp = (const float4*)(b1 + g * 16);
    const float4* wp = (const float4*)(w2 + g * 16);
#pragma unroll
    for (int i = 0; i < 4; ++i) {
      float4 bv = bp[i];
      float4 wv = wp[i];
      a[i * 4 + 0] = (i < 2 ? bf2f(a0[i * 4 + 0]) : bf2f(a1[i * 4 - 8])) + bv.x;
      a[i * 4 + 1] = (i < 2 ? bf2f(a0[i * 4 + 1]) : bf2f(a1[i * 4 - 7])) + bv.y;
      a[i * 4 + 2] = (i < 2 ? bf2f(a0[i * 4 + 2]) : bf2f(a1[i * 4 - 6])) + bv.z;
      a[i * 4 + 3] = (i < 2 ? bf2f(a0[i * 4 + 3]) : bf2f(a1[i * 4 - 5])) + bv.w;
      w[i * 4 + 0] = wv.x;
      w[i * 4 + 1] = wv.y;
      w[i * 4 + 2] = wv.z;
      w[i * 4 + 3] = wv.w;
    }
  }
  float base = b2[0];
  const unsigned short* Bb = Bm + g * 16;
  int e0 = beg + q;
  int2 m0 = (e0 < end) ? eto[e0] : make_int2(0, -1);
  u16x8 r0a = *(const u16x8*)(Bb + (size_t)m0.x * 256);
  u16x8 r0b = *(const u16x8*)(Bb + (size_t)m0.x * 256 + 8);
  for (int jb = beg; jb < end; jb += 4) {
    int2 m1 = make_int2(0, -1);
    u16x8 r1a = r0a, r1b = r0b;
    if (jb + 4 < end) {
      int e1 = jb + 4 + q;
      m1 = (e1 < end) ? eto[e1] : make_int2(0, -1);
      r1a = *(const u16x8*)(Bb + (size_t)m1.x * 256);
      r1b = *(const u16x8*)(Bb + (size_t)m1.x * 256 + 8);
    }
    float s = 0.f;
#pragma unroll
    for (int c = 0; c < 8; ++c) s += fmaxf(a[c] + bf2f(r0a[c]), 0.f) * w[c];
#pragma unroll
    for (int c = 0; c < 8; ++c) s += fmaxf(a[8 + c] + bf2f(r0b[c]), 0.f) * w[8 + c];
    s += __shfl_xor(s, 1, 64);
    s += __shfl_xor(s, 2, 64);
    s += __shfl_xor(s, 4, 64);
    s += __shfl_xor(s, 8, 64);
    if (g == 0 && m0.y >= 0) out[m0.y] = s + base;
    m0 = m1; r0a = r1a; r0b = r1b;
  }
}

extern "C" void kernel_launch(void* const* d_in, const int* in_sizes, int n_in,
                              void* d_out, int out_size, void* d_ws, size_t ws_size,
                              hipStream_t stream) {
  const float* x      = (const float*)d_in[0];
  const int*   ei     = (const int*)d_in[1];
  const float* attr   = (const float*)d_in[2];
  const int*   ewi    = (const int*)d_in[3];
  const float* p_pool = (const float*)d_in[4];
  const float* W_ih   = (const float*)d_in[5];
  const float* W_hh   = (const float*)d_in[6];
  const float* b_ih   = (const float*)d_in[7];
  const float* b_hh   = (const float*)d_in[8];
  const float* W_init = (const float*)d_in[9];
  const float* lin1_w = (const float*)d_in[10];
  const float* lin1_b = (const float*)d_in[11];
  const float* lin2_w = (const float*)d_in[12];
  const float* lin2_b = (const float*)d_in[13];
  float* out = (float*)d_out;

  const int C = 256;
  const int N = in_sizes[0] / C;   // 50000
  const int E = in_sizes[2];       // 800000

  // ---- workspace layout (256B aligned) ----
  char* ws = (char*)d_ws;
  size_t off = 0;
  auto alloc = [&](size_t bytes) {
    size_t o = off;
    off = (off + bytes + 255) & ~(size_t)255;
    return o;
  };
  float*          score  = (float*)(ws + alloc((size_t)N * 4));
  int*            perm   = (int*)(ws + alloc(C * 4));
  float*          tts    = (float*)(ws + alloc(C * 4));
  unsigned short* WevoT  = (unsigned short*)(ws + alloc((size_t)C * C * 2));
  unsigned short* WA     = (unsigned short*)(ws + alloc((size_t)C * C * 2));
  unsigned short* WB     = (unsigned short*)(ws + alloc((size_t)C * C * 2));
  // contiguous zero region: ghist | bcnt1 | bcnt2
  int   zeroInts = 4096 + 128 + 128;
  char* zbase    = ws + alloc((size_t)zeroInts * 4);
  int* ghist = (int*)zbase;
  int* bcnt1 = (int*)(zbase + 4096 * 4);
  int* bcnt2 = (int*)(zbase + 4096 * 4 + 128 * 4);
  int*            bbase1 = (int*)(ws + alloc((NBUCK + 1) * 4));
  int*            bbase2 = (int*)(ws + alloc((NBUCK + 1) * 4));
  int*            gcur1  = (int*)(ws + alloc(128 * 4));
  int*            gcur2  = (int*)(ws + alloc(128 * 4));
  float*          dinv   = (float*)(ws + alloc((size_t)N * 4));
  int*            rowp1  = (int*)(ws + alloc((size_t)(N + 1) * 4));
  int*            rowp2  = (int*)(ws + alloc((size_t)(N + 1) * 4));
  int2*           stage1 = (int2*)(ws + alloc((size_t)E * 8));
  int2*           stage2 = (int2*)(ws + alloc((size_t)E * 8));
  int2*           esv    = (int2*)(ws + alloc((size_t)E * 8));
  int2*           eto    = (int2*)(ws + alloc((size_t)E * 8));
  unsigned short* xh     = (unsigned short*)(ws + alloc((size_t)N * C * 2));
  unsigned short* xwh    = (unsigned short*)(ws + alloc((size_t)N * C * 2));
  unsigned short* Bbf    = (unsigned short*)(ws + alloc((size_t)N * C * 2));
  // aliases (stream-ordered producers/consumers):
  unsigned short* ne  = xh;   // xh dead after GEMM1
  unsigned short* Abf = xwh;  // xwh dead after gather

  // 0) zero ghist/bcnt in one tiny launch
  zero_kernel<<<(zeroInts / 4 + 255) / 256, 256, 0, stream>>>((float4*)zbase, zeroInts / 4);

  // 1) score (+||p||) + bf16 cast of x
  score_cast_kernel<<<(N + 3) / 4, 256, 0, stream>>>(x, p_pool, score, xh, N);

  // 2) exact top-256: LDS-aggregated histogram -> fused select+collect+sort
  hist12_kernel<<<64, 256, 0, stream>>>(score, N, ghist);
  topk_kernel<<<1, 1024, 0, stream>>>(score, N, C, ghist, perm, tts);

  // 3+4) GRU (x_tilde inline) -> evolved W (transposed bf16)
  gru_kernel<<<C, C, 0, stream>>>(x, perm, tts, W_init, W_ih, W_hh, b_ih, b_hh, WevoT);

  // 5) xw = x @ Wevo (bf16 MFMA, bf16 out)
  mfma_gemm_bf16<<<(N + 63) / 64, 256, 0, stream>>>(xh, WevoT, xwh, N);

  // 6) two-phase bucket sort for both CSRs (also produces deg/dinv in p2)
  bucket_hist_kernel<<<256, 256, 0, stream>>>(ei, ewi, bcnt1, bcnt2, E);
  bucket_scan_kernel<<<1, 128, 0, stream>>>(bcnt1, bcnt2, bbase1, bbase2, gcur1, gcur2,
                                            rowp1, rowp2, N, E);
  p1_conv_kernel<<<(E + 4095) / 4096, 256, 0, stream>>>(ei, attr, gcur1, stage1, E);
  p1_dec_kernel<<<(E + 4095) / 4096, 256, 0, stream>>>(ewi, gcur2, stage2, E);
  p2_kernel<<<2 * NBUCK, 256, 0, stream>>>(stage1, bbase1, esv, rowp1, dinv,
                                           stage2, bbase2, eto, rowp2, N);

  // 7) gather (quad decomposition)
  gcn_gather<<<(N + 3) / 4, 256, 0, stream>>>(xwh, rowp1, esv, dinv, ne, N);

  // 8) decoder projections fused (lin1_w rows ARE the B^T layout)
  lin1_cast_kernel<<<(2 * C * C) / 256, 256, 0, stream>>>(lin1_w, WA, WB);
  mfma_gemm_bf16_dual<<<(N + 63) / 64, 256, 0, stream>>>(ne, WA, WB, Abf, Bbf, N);

  // 9) edge decode (quad decomposition)
  edge_decode_csr<<<(N + 3) / 4, 256, 0, stream>>>(Abf, Bbf, rowp2, eto,
                                                   lin1_b, lin2_w, lin2_b, out, N);
}